// Round 18
// baseline (165.650 us; speedup 1.0000x reference)
//
#include <hip/hip_runtime.h>

// Problem constants
#define B_    2
#define S_    2048
#define E_    1024
#define H_    16
#define D_    64
#define M_    4096      // B*S
#define NQKV  3072
#define K_    1024

typedef __bf16 bf16;
typedef __attribute__((ext_vector_type(4))) __bf16 bf16x4;
typedef __attribute__((ext_vector_type(8))) __bf16 bf16x8;
typedef __attribute__((ext_vector_type(4))) float  f32x4;
typedef __attribute__((ext_vector_type(16))) float f32x16;

// Q pre-scale: 1/sqrt(64) * log2(e)  (softmax done in base-2 domain)
#define QSCALE 0.18033688f

// raw v_exp_f32 (TRANS pipe, 1 inst) — safe: args <= 8 (defer-max bound)
#define EXP2R(x) __builtin_amdgcn_exp2f(x)

// async global->LDS, 16B per lane; LDS dest must be wave-uniform base
__device__ __forceinline__ void gload_lds16(const void* g, void* l) {
    __builtin_amdgcn_global_load_lds(
        (const __attribute__((address_space(1))) void*)g,
        (__attribute__((address_space(3))) void*)l, 16, 0, 0);
}

// ---------------------------------------------------------------------------
// Kernel 1 (merged prep): x cast (blocks 0..4095), W_qkv transpose
// (4096..7167), W_out transpose (7168..8191).
// ---------------------------------------------------------------------------
__global__ __launch_bounds__(256) void prep_kernel(
    const float* __restrict__ x,     bf16* __restrict__ xb,
    const float* __restrict__ W_qkv, bf16* __restrict__ WqkvT,
    const float* __restrict__ W_out, bf16* __restrict__ WoutT)
{
    __shared__ bf16 tile[32][33];
    const int bid = blockIdx.x;
    if (bid < 4096) {
        int i = (bid * 256 + threadIdx.x) * 4;
        float4 v = *reinterpret_cast<const float4*>(x + i);
        bf16x4 o = { (bf16)v.x, (bf16)v.y, (bf16)v.z, (bf16)v.w };
        *reinterpret_cast<bf16x4*>(xb + i) = o;
        return;
    }
    const float* W; bf16* WT; int Ncols, bj, bi;
    if (bid < 4096 + 3072) {
        int t = bid - 4096;                    // W_qkv: 96 x 32 tiles
        W = W_qkv; WT = WqkvT; Ncols = NQKV;
        bj = t % 96; bi = t / 96;
    } else {
        int t = bid - 7168;                    // W_out: 32 x 32 tiles
        W = W_out; WT = WoutT; Ncols = E_;
        bj = t % 32; bi = t / 32;
    }
    int tx = threadIdx.x & 31;
    int ty = threadIdx.x >> 5;
#pragma unroll
    for (int it = 0; it < 4; ++it) {
        int r = ty + it * 8;
        tile[r][tx] = (bf16)W[(size_t)(bi * 32 + r) * Ncols + bj * 32 + tx];
    }
    __syncthreads();
#pragma unroll
    for (int it = 0; it < 4; ++it) {
        int r = ty + it * 8;
        WT[(size_t)(bj * 32 + r) * K_ + bi * 32 + tx] = tile[tx][r];
    }
}

// ---------------------------------------------------------------------------
// Shared GEMM mainloop (m97 structure): C_tile(128x128) = A[M][K] * BT[N][K]^T
// ---------------------------------------------------------------------------
__device__ __forceinline__ void gemm_tile_128(
    const bf16* __restrict__ A, const bf16* __restrict__ BT, int K,
    int bm0, int bn0, f32x4 acc[4][4])
{
    __shared__ bf16 sA[128 * 32];
    __shared__ bf16 sB[128 * 32];
    const int tid  = threadIdx.x;
    const int lane = tid & 63;
    const int wave = tid >> 6;
    const int g    = lane >> 4;
    const int r    = lane & 15;
    const int wr   = wave >> 1, wc = wave & 1;
    const int lrow = lane >> 2;          // 0..15
    const int lcol = (lane & 3) * 8;     // 0,8,16,24 elements

#pragma unroll
    for (int m = 0; m < 4; ++m)
#pragma unroll
        for (int n = 0; n < 4; ++n) acc[m][n] = (f32x4){0.f, 0.f, 0.f, 0.f};

    for (int k0 = 0; k0 < K; k0 += 32) {
#pragma unroll
        for (int j = 0; j < 2; ++j) {
            int r0 = wave * 32 + j * 16;
            gload_lds16(A  + (size_t)(bm0 + r0 + lrow) * K + k0 + lcol, &sA[r0 * 32]);
            gload_lds16(BT + (size_t)(bn0 + r0 + lrow) * K + k0 + lcol, &sB[r0 * 32]);
        }
        __syncthreads();
        bf16x8 af[4], bfr[4];
#pragma unroll
        for (int m = 0; m < 4; ++m)
            af[m] = *reinterpret_cast<const bf16x8*>(&sA[(wr * 64 + m * 16 + r) * 32 + g * 8]);
#pragma unroll
        for (int n = 0; n < 4; ++n)
            bfr[n] = *reinterpret_cast<const bf16x8*>(&sB[(wc * 64 + n * 16 + r) * 32 + g * 8]);
        __builtin_amdgcn_s_setprio(1);
#pragma unroll
        for (int m = 0; m < 4; ++m)
#pragma unroll
            for (int n = 0; n < 4; ++n)
                acc[m][n] = __builtin_amdgcn_mfma_f32_16x16x32_bf16(af[m], bfr[n], acc[m][n], 0, 0, 0);
        __builtin_amdgcn_s_setprio(0);
        __syncthreads();
    }
}

// ---------------------------------------------------------------------------
// Kernel 3: QKV projection -> Q (pre-scaled), K as [BH][S][64]; V transposed
// to Vt [BH][64][S] with the PV key-permutation baked in (s' = swap bits 2,3).
// ---------------------------------------------------------------------------
__global__ __launch_bounds__(256) void gemm_qkv(
    const bf16* __restrict__ xb, const bf16* __restrict__ WT,
    const float* __restrict__ bias,
    bf16* __restrict__ Qb, bf16* __restrict__ Kb, bf16* __restrict__ Vt)
{
    f32x4 acc[4][4];
    const int bid = blockIdx.y * 24 + blockIdx.x;   // 0..767
    const int swz = (bid & 7) * 96 + (bid >> 3);    // bijective
    int bm0 = (swz / 24) * 128, bn0 = (swz % 24) * 128;
    gemm_tile_128(xb, WT, K_, bm0, bn0, acc);

    const int lane = threadIdx.x & 63, wave = threadIdx.x >> 6;
    const int g = lane >> 4, c = lane & 15;
    const int wr = wave >> 1, wc = wave & 1;
#pragma unroll
    for (int m = 0; m < 4; ++m) {
        int ibase = bm0 + wr * 64 + m * 16 + 4 * g;
        int b = ibase >> 11, s = ibase & 2047;   // 4 consecutive rows, same b
        int sp = (s & ~12) | ((s & 4) << 1) | ((s & 8) >> 1);
#pragma unroll
        for (int n = 0; n < 4; ++n) {
            int j = bn0 + wc * 64 + n * 16 + c;
            int h = j / 192, w = j % 192;
            int t = w >> 6, d = w & 63;
            float bj = bias[j];
            if (t == 2) {
                bf16x4 v4 = { (bf16)(acc[m][n][0] + bj), (bf16)(acc[m][n][1] + bj),
                              (bf16)(acc[m][n][2] + bj), (bf16)(acc[m][n][3] + bj) };
                *reinterpret_cast<bf16x4*>(
                    &Vt[((size_t)((b * H_ + h) * D_ + d)) * S_ + sp]) = v4;
            } else {
                bf16* dst = (t == 0) ? Qb : Kb;
                float scale = (t == 0) ? QSCALE : 1.0f;
#pragma unroll
                for (int jj = 0; jj < 4; ++jj) {
                    size_t idx = ((size_t)((b * H_ + h) * S_ + s + jj)) * D_ + d;
                    dst[idx] = (bf16)((acc[m][n][jj] + bj) * scale);
                }
            }
        }
    }
}

// Merged softmax + pack + PV for one 64-key phase (names must be unique).
// Updates m_run, l_run, acc[]; reads scA/scB (two 32-key score slices).
#define SOFTMAX_PV(scA, scB, BASE)                                             \
    {                                                                          \
        float a0 = fmaxf(fmaxf(scA[0], scA[1]), scA[2]);                       \
        float a1 = fmaxf(fmaxf(scA[3], scA[4]), scA[5]);                       \
        float a2 = fmaxf(fmaxf(scA[6], scA[7]), scA[8]);                       \
        float a3 = fmaxf(fmaxf(scA[9], scA[10]), scA[11]);                     \
        float a4 = fmaxf(fmaxf(scA[12], scA[13]), scA[14]);                    \
        float a5 = fmaxf(fmaxf(scB[0], scB[1]), scB[2]);                       \
        float a6 = fmaxf(fmaxf(scB[3], scB[4]), scB[5]);                       \
        float a7 = fmaxf(fmaxf(scB[6], scB[7]), scB[8]);                       \
        float a8 = fmaxf(fmaxf(scB[9], scB[10]), scB[11]);                     \
        float a9 = fmaxf(fmaxf(scB[12], scB[13]), scB[14]);                    \
        float b0 = fmaxf(fmaxf(a0, a1), scA[15]);                              \
        float b1 = fmaxf(fmaxf(a2, a3), a4);                                   \
        float b2 = fmaxf(fmaxf(a5, a6), scB[15]);                              \
        float b3 = fmaxf(fmaxf(a7, a8), a9);                                   \
        float vmax = fmaxf(fmaxf(b0, b1), fmaxf(b2, b3));                      \
        vmax = fmaxf(vmax, __shfl_xor(vmax, 32));                              \
        if (__any(vmax > m_run + 8.0f)) {                                      \
            float mnew = fmaxf(m_run, vmax);                                   \
            float f = EXP2R(m_run - mnew);                                     \
            l_run *= f;                                                        \
            for (int t = 0; t < 2; ++t) acc[t] *= f;                           \
            m_run = mnew;                                                      \
        }                                                                      \
        float p0[16], p1[16];                                                  \
        _Pragma("unroll")                                                      \
        for (int r = 0; r < 16; ++r) p0[r] = EXP2R(scA[r] - m_run);            \
        _Pragma("unroll")                                                      \
        for (int r = 0; r < 16; ++r) p1[r] = EXP2R(scB[r] - m_run);            \
        {                                                                      \
            float s0 = ((p0[0] + p0[1]) + (p0[2] + p0[3])) +                   \
                       ((p0[4] + p0[5]) + (p0[6] + p0[7]));                    \
            float s1 = ((p0[8] + p0[9]) + (p0[10] + p0[11])) +                 \
                       ((p0[12] + p0[13]) + (p0[14] + p0[15]));                \
            float s2 = ((p1[0] + p1[1]) + (p1[2] + p1[3])) +                   \
                       ((p1[4] + p1[5]) + (p1[6] + p1[7]));                    \
            float s3 = ((p1[8] + p1[9]) + (p1[10] + p1[11])) +                 \
                       ((p1[12] + p1[13]) + (p1[14] + p1[15]));                \
            l_run += (s0 + s1) + (s2 + s3);                                    \
        }                                                                      \
        unsigned w0[8], w1[8];                                                 \
        _Pragma("unroll")                                                      \
        for (int b = 0; b < 4; ++b) {                                          \
            union { bf16 x; unsigned short u; } c0, c1, c2, c3, d0, d1, d2, d3;\
            c0.x = (bf16)p0[4 * b + 0]; c1.x = (bf16)p0[4 * b + 1];            \
            c2.x = (bf16)p0[4 * b + 2]; c3.x = (bf16)p0[4 * b + 3];            \
            d0.x = (bf16)p1[4 * b + 0]; d1.x = (bf16)p1[4 * b + 1];            \
            d2.x = (bf16)p1[4 * b + 2]; d3.x = (bf16)p1[4 * b + 3];            \
            w0[2 * b]     = (unsigned)c0.u | ((unsigned)c1.u << 16);           \
            w0[2 * b + 1] = (unsigned)c2.u | ((unsigned)c3.u << 16);           \
            w1[2 * b]     = (unsigned)d0.u | ((unsigned)d1.u << 16);           \
            w1[2 * b + 1] = (unsigned)d2.u | ((unsigned)d3.u << 16);           \
        }                                                                      \
        _Pragma("unroll")                                                      \
        for (int ks = 0; ks < 2; ++ks) {                                       \
            const unsigned* w = ks ? w1 : w0;                                  \
            _Pragma("unroll")                                                  \
            for (int kk = 0; kk < 2; ++kk) {                                   \
                union { bf16x8 v; unsigned u[4]; } pf;                         \
                pf.u[0] = w[4 * kk];     pf.u[1] = w[4 * kk + 1];              \
                pf.u[2] = w[4 * kk + 2]; pf.u[3] = w[4 * kk + 3];              \
                __builtin_amdgcn_s_setprio(1);                                 \
                _Pragma("unroll")                                              \
                for (int t = 0; t < 2; ++t) {                                  \
                    bf16x8 vf = *reinterpret_cast<const bf16x8*>(              \
                        &sVh[(32 * t + c) * 136 + (BASE) + ks * 32 + kk * 16 + 8 * h]); \
                    acc[t] = __builtin_amdgcn_mfma_f32_32x32x16_bf16(vf, pf.v, acc[t], 0, 0, 0); \
                }                                                              \
                __builtin_amdgcn_s_setprio(0);                                 \
            }                                                                  \
        }                                                                      \
    }

// ---------------------------------------------------------------------------
// Kernel 4: flash attention — round-17 structure with ONE change: all 16 QK
// MFMAs for the 128-key tile issue up front (4 independent chains); phase 0's
// softmax/pack/PV runs while phase 1's QK results are in flight.
// ---------------------------------------------------------------------------
__global__ __launch_bounds__(512, 4) void attn_kernel(
    const bf16* __restrict__ Qb, const bf16* __restrict__ Kb,
    const bf16* __restrict__ Vt, bf16* __restrict__ Ob)
{
    // LDS map (bytes):
    // [0, 36864)       sK[2 half][128][72] bf16
    // [36864, 71680)   sV[2 half][64][136] bf16
    // [0, 33792)       mrg[4*64*33] f32   (ALIAS: used only after compute)
    // [71680, 72704)   ml[4][32][2] f32
    __shared__ __align__(16) char smem[72704];

    const int bh  = blockIdx.y;          // b*16 + h
    const int q0  = blockIdx.x * 128;
    const int tid = threadIdx.x, lane = tid & 63;
    const int qw   = (tid >> 6) & 3;     // q sub-tile
    const int half = tid >> 8;           // KV half
    const int gtid = tid & 255;          // tid within half-group
    const int c = lane & 31;             // q column (QK), d row (PV A), key row (K frag)
    const int h = lane >> 5;             // k-slice half

    bf16* sKh = reinterpret_cast<bf16*>(smem) + half * (128 * 72);
    bf16* sVh = reinterpret_cast<bf16*>(smem + 36864) + half * (64 * 136);
    float* mrg = reinterpret_cast<float*>(smem);
    float* ml  = reinterpret_cast<float*>(smem + 71680);

    const bf16* Qp = Qb + (size_t)bh * S_ * D_;
    const bf16* Kp = Kb + (size_t)bh * S_ * D_ + (size_t)half * 1024 * D_;
    const bf16* Vp = Vt + (size_t)bh * D_ * S_ + half * 1024;   // [64][2048]

    // Q fragments (B-operand): lane needs Q[q=qrow][d = kk*16 + 8h .. +7]
    const int qrow = q0 + qw * 32 + c;
    bf16x8 qf[4];
#pragma unroll
    for (int kk = 0; kk < 4; ++kk)
        qf[kk] = *reinterpret_cast<const bf16x8*>(Qp + (size_t)qrow * D_ + kk * 16 + 8 * h);

    f32x16 acc[2];
#pragma unroll
    for (int t = 0; t < 2; ++t) acc[t] = (f32x16)(0.f);
    float m_run = -1e30f, l_run = 0.f;

    const int srowK = gtid >> 3, sgiK = (gtid & 7) * 8;    // K: 32 rows/pass x 8 chunks
    const int srowV = gtid >> 4, sgiV = (gtid & 15) * 8;   // V: 16 rows/pass x 16 chunks

    for (int kv0 = 0; kv0 < 1024; kv0 += 128) {
        __syncthreads();
        // stage K[128 keys][64 d] and Vt[64 d][128 keys] for this half
#pragma unroll
        for (int i = 0; i < 4; ++i) {
            int rK = srowK + i * 32;
            *reinterpret_cast<uint4*>(&sKh[rK * 72 + sgiK]) =
                *reinterpret_cast<const uint4*>(Kp + (size_t)(kv0 + rK) * D_ + sgiK);
            int rV = srowV + i * 16;
            *reinterpret_cast<uint4*>(&sVh[rV * 136 + sgiV]) =
                *reinterpret_cast<const uint4*>(Vp + (size_t)rV * S_ + kv0 + sgiV);
        }
        __syncthreads();

        // ---- QK^T for ALL 128 keys up front (4 independent chains) ----
        f32x16 sc00 = (f32x16)(0.f), sc01 = (f32x16)(0.f);
        f32x16 sc10 = (f32x16)(0.f), sc11 = (f32x16)(0.f);
        __builtin_amdgcn_s_setprio(1);
#pragma unroll
        for (int kk = 0; kk < 4; ++kk) {
            bf16x8 kf0 = *reinterpret_cast<const bf16x8*>(
                &sKh[(c) * 72 + kk * 16 + 8 * h]);
            bf16x8 kf1 = *reinterpret_cast<const bf16x8*>(
                &sKh[(32 + c) * 72 + kk * 16 + 8 * h]);
            bf16x8 kf2 = *reinterpret_cast<const bf16x8*>(
                &sKh[(64 + c) * 72 + kk * 16 + 8 * h]);
            bf16x8 kf3 = *reinterpret_cast<const bf16x8*>(
                &sKh[(96 + c) * 72 + kk * 16 + 8 * h]);
            sc00 = __builtin_amdgcn_mfma_f32_32x32x16_bf16(kf0, qf[kk], sc00, 0, 0, 0);
            sc01 = __builtin_amdgcn_mfma_f32_32x32x16_bf16(kf1, qf[kk], sc01, 0, 0, 0);
            sc10 = __builtin_amdgcn_mfma_f32_32x32x16_bf16(kf2, qf[kk], sc10, 0, 0, 0);
            sc11 = __builtin_amdgcn_mfma_f32_32x32x16_bf16(kf3, qf[kk], sc11, 0, 0, 0);
        }
        __builtin_amdgcn_s_setprio(0);

        // phase 0 softmax/pack/PV (phase 1's QK results still in flight)
        SOFTMAX_PV(sc00, sc01, 0)
        // phase 1
        SOFTMAX_PV(sc10, sc11, 64)
    }

    // ---- flash-decoding merge across the two KV halves ----
    float l_tot = l_run + __shfl_xor(l_run, 32);   // full l for this half

    __syncthreads();                                // all compute done; mrg alias safe
    if (half == 1) {
        float4* dst = reinterpret_cast<float4*>(&mrg[(qw * 64 + lane) * 33]);
#pragma unroll
        for (int t = 0; t < 2; ++t)
#pragma unroll
            for (int v = 0; v < 4; ++v)
                dst[t * 4 + v] = make_float4(acc[t][4 * v + 0], acc[t][4 * v + 1],
                                             acc[t][4 * v + 2], acc[t][4 * v + 3]);
        if (lane < 32) { ml[(qw * 32 + lane) * 2 + 0] = m_run;
                         ml[(qw * 32 + lane) * 2 + 1] = l_tot; }
    }
    __syncthreads();

    if (half == 0) {
        float m1 = ml[(qw * 32 + c) * 2 + 0], l1 = ml[(qw * 32 + c) * 2 + 1];
        float mm = fmaxf(m_run, m1);
        float f0 = EXP2R(m_run - mm), f1 = EXP2R(m1 - mm);
        float li = 1.0f / (l_tot * f0 + l1 * f1);
        float g0 = f0 * li, g1 = f1 * li;
        const float4* src = reinterpret_cast<const float4*>(&mrg[(qw * 64 + lane) * 33]);
        float o[2][16];
#pragma unroll
        for (int t = 0; t < 2; ++t)
#pragma unroll
            for (int v = 0; v < 4; ++v) {
                float4 a1 = src[t * 4 + v];
                o[t][4 * v + 0] = acc[t][4 * v + 0] * g0 + a1.x * g1;
                o[t][4 * v + 1] = acc[t][4 * v + 1] * g0 + a1.y * g1;
                o[t][4 * v + 2] = acc[t][4 * v + 2] * g0 + a1.z * g1;
                o[t][4 * v + 3] = acc[t][4 * v + 3] * g0 + a1.w * g1;
            }

        // transpose O^T -> O rows via (reused) wave-private LDS region
        bf16* so = reinterpret_cast<bf16*>(&mrg[(size_t)qw * 64 * 33]);
#pragma unroll
        for (int t = 0; t < 2; ++t)
#pragma unroll
            for (int b = 0; b < 4; ++b) {
                bf16x4 v4 = { (bf16)o[t][4 * b + 0], (bf16)o[t][4 * b + 1],
                              (bf16)o[t][4 * b + 2], (bf16)o[t][4 * b + 3] };
                // d = 32t + 8b + 4h + {0..3}, q = c
                *reinterpret_cast<bf16x4*>(&so[c * 72 + t * 32 + b * 8 + 4 * h]) = v4;
            }
        const int bb = bh >> 4, hh = bh & 15;
#pragma unroll
        for (int i = 0; i < 4; ++i) {
            int chunk = lane + 64 * i;         // 256 chunks = 32 rows x 8
            int row = chunk >> 3, gi = chunk & 7;
            uint4 val = *reinterpret_cast<uint4*>(&so[row * 72 + gi * 8]);
            *reinterpret_cast<uint4*>(
                Ob + ((size_t)(bb * S_ + q0 + qw * 32 + row)) * E_ + hh * 64 + gi * 8) = val;
        }
    }
}

// ---------------------------------------------------------------------------
// Kernel 5: output projection, 64x128 tile (2 blocks/CU).
// ---------------------------------------------------------------------------
__global__ __launch_bounds__(256) void gemm_out(
    const bf16* __restrict__ Ob, const bf16* __restrict__ WT,
    const float* __restrict__ bias, float* __restrict__ out)
{
    __shared__ bf16 sA[64 * 32];
    __shared__ bf16 sB[128 * 32];
    const int tid  = threadIdx.x;
    const int lane = tid & 63;
    const int wave = tid >> 6;
    const int g    = lane >> 4;
    const int r    = lane & 15;
    const int wr   = wave >> 1, wc = wave & 1;   // waves 2x2: 32 rows x 64 cols each
    const int lrow = lane >> 2;
    const int lcol = (lane & 3) * 8;
    const int bm0 = blockIdx.y * 64, bn0 = blockIdx.x * 128;

    f32x4 acc[2][4];
#pragma unroll
    for (int m = 0; m < 2; ++m)
#pragma unroll
        for (int n = 0; n < 4; ++n) acc[m][n] = (f32x4){0.f, 0.f, 0.f, 0.f};

    for (int k0 = 0; k0 < K_; k0 += 32) {
        // A: 64 rows, each wave stages 16
        gload_lds16(Ob + (size_t)(bm0 + wave * 16 + lrow) * K_ + k0 + lcol,
                    &sA[(wave * 16) * 32]);
        // B: 128 rows, each wave stages 32
#pragma unroll
        for (int j = 0; j < 2; ++j) {
            int r0 = wave * 32 + j * 16;
            gload_lds16(WT + (size_t)(bn0 + r0 + lrow) * K_ + k0 + lcol, &sB[r0 * 32]);
        }
        __syncthreads();
        bf16x8 af[2], bfr[4];
#pragma unroll
        for (int m = 0; m < 2; ++m)
            af[m] = *reinterpret_cast<const bf16x8*>(&sA[(wr * 32 + m * 16 + r) * 32 + g * 8]);
#pragma unroll
        for (int n = 0; n < 4; ++n)
            bfr[n] = *reinterpret_cast<const bf16x8*>(&sB[(wc * 64 + n * 16 + r) * 32 + g * 8]);
        __builtin_amdgcn_s_setprio(1);
#pragma unroll
        for (int m = 0; m < 2; ++m)
#pragma unroll
            for (int n = 0; n < 4; ++n)
                acc[m][n] = __builtin_amdgcn_mfma_f32_16x16x32_bf16(af[m], bfr[n], acc[m][n], 0, 0, 0);
        __builtin_amdgcn_s_setprio(0);
        __syncthreads();
    }

#pragma unroll
    for (int m = 0; m < 2; ++m) {
        int ibase = bm0 + wr * 32 + m * 16 + 4 * g;
#pragma unroll
        for (int n = 0; n < 4; ++n) {
            int j = bn0 + wc * 64 + n * 16 + r;
            float bj = bias[j];
#pragma unroll
            for (int jj = 0; jj < 4; ++jj) {
                int row = ibase + jj;
                out[(size_t)row * E_ + j] = acc[m][n][jj] + bj;
            }
        }
    }
}

// ---------------------------------------------------------------------------
extern "C" void kernel_launch(void* const* d_in, const int* in_sizes, int n_in,
                              void* d_out, int out_size, void* d_ws, size_t ws_size,
                              hipStream_t stream)
{
    const float* x     = (const float*)d_in[0];
    const float* W_qkv = (const float*)d_in[1];
    const float* b_qkv = (const float*)d_in[2];
    const float* W_out = (const float*)d_in[3];
    const float* b_out = (const float*)d_in[4];
    float* out = (float*)d_out;

    char* ws = (char*)d_ws;
    bf16* xb    = (bf16*)(ws);                 //  8 MB  [4096][1024]
    bf16* WqkvT = (bf16*)(ws + (8u  << 20));   //  6 MB
    bf16* WoutT = (bf16*)(ws + (14u << 20));   //  2 MB
    bf16* Qb    = (bf16*)(ws + (16u << 20));   //  8 MB  [32][2048][64]
    bf16* Kb    = (bf16*)(ws + (24u << 20));   //  8 MB
    bf16* Vt    = (bf16*)(ws + (32u << 20));   //  8 MB  [32][64][2048] (permuted)
    bf16* Ob    = (bf16*)(ws + (40u << 20));   //  8 MB

    prep_kernel<<<8192, 256, 0, stream>>>(x, xb, W_qkv, WqkvT, W_out, WoutT);
    gemm_qkv<<<dim3(NQKV / 128, M_ / 128), 256, 0, stream>>>(xb, WqkvT, b_qkv, Qb, Kb, Vt);
    attn_kernel<<<dim3(S_ / 128, B_ * H_), 512, 0, stream>>>(Qb, Kb, Vt, Ob);
    gemm_out<<<dim3(E_ / 128, M_ / 64), 256, 0, stream>>>(Ob, WoutT, b_out, out);
}

// Round 19
// 127.022 us; speedup vs baseline: 1.3041x; 1.3041x over previous
//
#include <hip/hip_runtime.h>

// Problem constants
#define B_    2
#define S_    2048
#define E_    1024
#define H_    16
#define D_    64
#define M_    4096      // B*S
#define NQKV  3072
#define K_    1024

typedef __bf16 bf16;
typedef __attribute__((ext_vector_type(4))) __bf16 bf16x4;
typedef __attribute__((ext_vector_type(8))) __bf16 bf16x8;
typedef __attribute__((ext_vector_type(4))) float  f32x4;
typedef __attribute__((ext_vector_type(16))) float f32x16;

// Q pre-scale: 1/sqrt(64) * log2(e)  (softmax done in base-2 domain)
#define QSCALE 0.18033688f

// raw v_exp_f32 (TRANS pipe, 1 inst) — safe: args <= 8 (defer-max bound)
#define EXP2R(x) __builtin_amdgcn_exp2f(x)

// async global->LDS, 16B per lane; LDS dest must be wave-uniform base
__device__ __forceinline__ void gload_lds16(const void* g, void* l) {
    __builtin_amdgcn_global_load_lds(
        (const __attribute__((address_space(1))) void*)g,
        (__attribute__((address_space(3))) void*)l, 16, 0, 0);
}

// ---------------------------------------------------------------------------
// Kernel 1 (merged prep): x cast (blocks 0..4095), W_qkv transpose
// (4096..7167), W_out transpose (7168..8191).
// ---------------------------------------------------------------------------
__global__ __launch_bounds__(256) void prep_kernel(
    const float* __restrict__ x,     bf16* __restrict__ xb,
    const float* __restrict__ W_qkv, bf16* __restrict__ WqkvT,
    const float* __restrict__ W_out, bf16* __restrict__ WoutT)
{
    __shared__ bf16 tile[32][33];
    const int bid = blockIdx.x;
    if (bid < 4096) {
        int i = (bid * 256 + threadIdx.x) * 4;
        float4 v = *reinterpret_cast<const float4*>(x + i);
        bf16x4 o = { (bf16)v.x, (bf16)v.y, (bf16)v.z, (bf16)v.w };
        *reinterpret_cast<bf16x4*>(xb + i) = o;
        return;
    }
    const float* W; bf16* WT; int Ncols, bj, bi;
    if (bid < 4096 + 3072) {
        int t = bid - 4096;                    // W_qkv: 96 x 32 tiles
        W = W_qkv; WT = WqkvT; Ncols = NQKV;
        bj = t % 96; bi = t / 96;
    } else {
        int t = bid - 7168;                    // W_out: 32 x 32 tiles
        W = W_out; WT = WoutT; Ncols = E_;
        bj = t % 32; bi = t / 32;
    }
    int tx = threadIdx.x & 31;
    int ty = threadIdx.x >> 5;
#pragma unroll
    for (int it = 0; it < 4; ++it) {
        int r = ty + it * 8;
        tile[r][tx] = (bf16)W[(size_t)(bi * 32 + r) * Ncols + bj * 32 + tx];
    }
    __syncthreads();
#pragma unroll
    for (int it = 0; it < 4; ++it) {
        int r = ty + it * 8;
        WT[(size_t)(bj * 32 + r) * K_ + bi * 32 + tx] = tile[tx][r];
    }
}

// ---------------------------------------------------------------------------
// Shared GEMM mainloop (m97 structure): C_tile(128x128) = A[M][K] * BT[N][K]^T
// ---------------------------------------------------------------------------
__device__ __forceinline__ void gemm_tile_128(
    const bf16* __restrict__ A, const bf16* __restrict__ BT, int K,
    int bm0, int bn0, f32x4 acc[4][4])
{
    __shared__ bf16 sA[128 * 32];
    __shared__ bf16 sB[128 * 32];
    const int tid  = threadIdx.x;
    const int lane = tid & 63;
    const int wave = tid >> 6;
    const int g    = lane >> 4;
    const int r    = lane & 15;
    const int wr   = wave >> 1, wc = wave & 1;
    const int lrow = lane >> 2;          // 0..15
    const int lcol = (lane & 3) * 8;     // 0,8,16,24 elements

#pragma unroll
    for (int m = 0; m < 4; ++m)
#pragma unroll
        for (int n = 0; n < 4; ++n) acc[m][n] = (f32x4){0.f, 0.f, 0.f, 0.f};

    for (int k0 = 0; k0 < K; k0 += 32) {
#pragma unroll
        for (int j = 0; j < 2; ++j) {
            int r0 = wave * 32 + j * 16;
            gload_lds16(A  + (size_t)(bm0 + r0 + lrow) * K + k0 + lcol, &sA[r0 * 32]);
            gload_lds16(BT + (size_t)(bn0 + r0 + lrow) * K + k0 + lcol, &sB[r0 * 32]);
        }
        __syncthreads();
        bf16x8 af[4], bfr[4];
#pragma unroll
        for (int m = 0; m < 4; ++m)
            af[m] = *reinterpret_cast<const bf16x8*>(&sA[(wr * 64 + m * 16 + r) * 32 + g * 8]);
#pragma unroll
        for (int n = 0; n < 4; ++n)
            bfr[n] = *reinterpret_cast<const bf16x8*>(&sB[(wc * 64 + n * 16 + r) * 32 + g * 8]);
        __builtin_amdgcn_s_setprio(1);
#pragma unroll
        for (int m = 0; m < 4; ++m)
#pragma unroll
            for (int n = 0; n < 4; ++n)
                acc[m][n] = __builtin_amdgcn_mfma_f32_16x16x32_bf16(af[m], bfr[n], acc[m][n], 0, 0, 0);
        __builtin_amdgcn_s_setprio(0);
        __syncthreads();
    }
}

// ---------------------------------------------------------------------------
// Kernel 3: QKV projection -> Q (pre-scaled), K as [BH][S][64]; V transposed
// to Vt [BH][64][S] with the PV key-permutation BAKED IN: column s stored at
// s' = swap-bits-2-3(s).  (PV's MFMA is invariant under a key permutation
// applied to both V columns and P rows; this permutation makes each lane's
// own P registers the exact B-fragment — no cross-lane exchange in attn.)
// ---------------------------------------------------------------------------
__global__ __launch_bounds__(256) void gemm_qkv(
    const bf16* __restrict__ xb, const bf16* __restrict__ WT,
    const float* __restrict__ bias,
    bf16* __restrict__ Qb, bf16* __restrict__ Kb, bf16* __restrict__ Vt)
{
    f32x4 acc[4][4];
    const int bid = blockIdx.y * 24 + blockIdx.x;   // 0..767
    const int swz = (bid & 7) * 96 + (bid >> 3);    // bijective
    int bm0 = (swz / 24) * 128, bn0 = (swz % 24) * 128;
    gemm_tile_128(xb, WT, K_, bm0, bn0, acc);

    const int lane = threadIdx.x & 63, wave = threadIdx.x >> 6;
    const int g = lane >> 4, c = lane & 15;
    const int wr = wave >> 1, wc = wave & 1;
#pragma unroll
    for (int m = 0; m < 4; ++m) {
        int ibase = bm0 + wr * 64 + m * 16 + 4 * g;
        int b = ibase >> 11, s = ibase & 2047;   // 4 consecutive rows, same b
        // key-group permutation: swap bits 2 and 3 of s (4-aligned groups)
        int sp = (s & ~12) | ((s & 4) << 1) | ((s & 8) >> 1);
#pragma unroll
        for (int n = 0; n < 4; ++n) {
            int j = bn0 + wc * 64 + n * 16 + c;
            int h = j / 192, w = j % 192;
            int t = w >> 6, d = w & 63;
            float bj = bias[j];
            if (t == 2) {
                // V: transposed + permuted store, s contiguous within group
                bf16x4 v4 = { (bf16)(acc[m][n][0] + bj), (bf16)(acc[m][n][1] + bj),
                              (bf16)(acc[m][n][2] + bj), (bf16)(acc[m][n][3] + bj) };
                *reinterpret_cast<bf16x4*>(
                    &Vt[((size_t)((b * H_ + h) * D_ + d)) * S_ + sp]) = v4;
            } else {
                bf16* dst = (t == 0) ? Qb : Kb;
                float scale = (t == 0) ? QSCALE : 1.0f;
#pragma unroll
                for (int jj = 0; jj < 4; ++jj) {
                    size_t idx = ((size_t)((b * H_ + h) * S_ + s + jj)) * D_ + d;
                    dst[idx] = (bf16)((acc[m][n][jj] + bj) * scale);
                }
            }
        }
    }
}

// ---------------------------------------------------------------------------
// Kernel 4: flash attention — round-17 version (best: 59.5 us).  Swapped
// QK^T 32x32, 2-way in-block KV-split, KVBLK=128, merged softmax, raw
// v_exp_f32, baked V permutation (PV B-fragment = lane's own P registers).
// ---------------------------------------------------------------------------
__global__ __launch_bounds__(512, 4) void attn_kernel(
    const bf16* __restrict__ Qb, const bf16* __restrict__ Kb,
    const bf16* __restrict__ Vt, bf16* __restrict__ Ob)
{
    // LDS map (bytes):
    // [0, 36864)       sK[2 half][128][72] bf16
    // [36864, 71680)   sV[2 half][64][136] bf16
    // [0, 33792)       mrg[4*64*33] f32   (ALIAS: used only after compute)
    // [71680, 72704)   ml[4][32][2] f32
    __shared__ __align__(16) char smem[72704];

    const int bh  = blockIdx.y;          // b*16 + h
    const int q0  = blockIdx.x * 128;
    const int tid = threadIdx.x, lane = tid & 63;
    const int qw   = (tid >> 6) & 3;     // q sub-tile
    const int half = tid >> 8;           // KV half
    const int gtid = tid & 255;          // tid within half-group
    const int c = lane & 31;             // q column (QK), d row (PV A), key row (K frag)
    const int h = lane >> 5;             // k-slice half

    bf16* sKh = reinterpret_cast<bf16*>(smem) + half * (128 * 72);
    bf16* sVh = reinterpret_cast<bf16*>(smem + 36864) + half * (64 * 136);
    float* mrg = reinterpret_cast<float*>(smem);
    float* ml  = reinterpret_cast<float*>(smem + 71680);

    const bf16* Qp = Qb + (size_t)bh * S_ * D_;
    const bf16* Kp = Kb + (size_t)bh * S_ * D_ + (size_t)half * 1024 * D_;
    const bf16* Vp = Vt + (size_t)bh * D_ * S_ + half * 1024;   // [64][2048]

    // Q fragments (B-operand): lane needs Q[q=qrow][d = kk*16 + 8h .. +7]
    const int qrow = q0 + qw * 32 + c;
    bf16x8 qf[4];
#pragma unroll
    for (int kk = 0; kk < 4; ++kk)
        qf[kk] = *reinterpret_cast<const bf16x8*>(Qp + (size_t)qrow * D_ + kk * 16 + 8 * h);

    f32x16 acc[2];
#pragma unroll
    for (int t = 0; t < 2; ++t) acc[t] = (f32x16)(0.f);
    float m_run = -1e30f, l_run = 0.f;

    const int srowK = gtid >> 3, sgiK = (gtid & 7) * 8;    // K: 32 rows/pass x 8 chunks
    const int srowV = gtid >> 4, sgiV = (gtid & 15) * 8;   // V: 16 rows/pass x 16 chunks

    for (int kv0 = 0; kv0 < 1024; kv0 += 128) {
        __syncthreads();
        // stage K[128 keys][64 d] and Vt[64 d][128 keys] for this half
#pragma unroll
        for (int i = 0; i < 4; ++i) {
            int rK = srowK + i * 32;
            *reinterpret_cast<uint4*>(&sKh[rK * 72 + sgiK]) =
                *reinterpret_cast<const uint4*>(Kp + (size_t)(kv0 + rK) * D_ + sgiK);
            int rV = srowV + i * 16;
            *reinterpret_cast<uint4*>(&sVh[rV * 136 + sgiV]) =
                *reinterpret_cast<const uint4*>(Vp + (size_t)rV * S_ + kv0 + sgiV);
        }
        __syncthreads();

#pragma unroll
        for (int ph = 0; ph < 2; ++ph) {
            const int base = ph * 64;
            // ---- QK^T for both 32-key slices (2 independent chains) ----
            f32x16 sc0 = (f32x16)(0.f), sc1 = (f32x16)(0.f);
            __builtin_amdgcn_s_setprio(1);
#pragma unroll
            for (int kk = 0; kk < 4; ++kk) {
                bf16x8 kf0 = *reinterpret_cast<const bf16x8*>(
                    &sKh[(base + c) * 72 + kk * 16 + 8 * h]);
                bf16x8 kf1 = *reinterpret_cast<const bf16x8*>(
                    &sKh[(base + 32 + c) * 72 + kk * 16 + 8 * h]);
                sc0 = __builtin_amdgcn_mfma_f32_32x32x16_bf16(kf0, qf[kk], sc0, 0, 0, 0);
                sc1 = __builtin_amdgcn_mfma_f32_32x32x16_bf16(kf1, qf[kk], sc1, 0, 0, 0);
            }
            __builtin_amdgcn_s_setprio(0);

            // ---- merged online softmax over 64 keys ----
            float a0 = fmaxf(fmaxf(sc0[0], sc0[1]), sc0[2]);
            float a1 = fmaxf(fmaxf(sc0[3], sc0[4]), sc0[5]);
            float a2 = fmaxf(fmaxf(sc0[6], sc0[7]), sc0[8]);
            float a3 = fmaxf(fmaxf(sc0[9], sc0[10]), sc0[11]);
            float a4 = fmaxf(fmaxf(sc0[12], sc0[13]), sc0[14]);
            float a5 = fmaxf(fmaxf(sc1[0], sc1[1]), sc1[2]);
            float a6 = fmaxf(fmaxf(sc1[3], sc1[4]), sc1[5]);
            float a7 = fmaxf(fmaxf(sc1[6], sc1[7]), sc1[8]);
            float a8 = fmaxf(fmaxf(sc1[9], sc1[10]), sc1[11]);
            float a9 = fmaxf(fmaxf(sc1[12], sc1[13]), sc1[14]);
            float b0 = fmaxf(fmaxf(a0, a1), sc0[15]);
            float b1 = fmaxf(fmaxf(a2, a3), a4);
            float b2 = fmaxf(fmaxf(a5, a6), sc1[15]);
            float b3 = fmaxf(fmaxf(a7, a8), a9);
            float vmax = fmaxf(fmaxf(b0, b1), fmaxf(b2, b3));
            vmax = fmaxf(vmax, __shfl_xor(vmax, 32));
            if (__any(vmax > m_run + 8.0f)) {     // defer-max, THR=8 (log2 domain)
                float mnew = fmaxf(m_run, vmax);
                float f = EXP2R(m_run - mnew);
                l_run *= f;
#pragma unroll
                for (int t = 0; t < 2; ++t) acc[t] *= f;
                m_run = mnew;
            }
            float p0[16], p1[16];
#pragma unroll
            for (int r = 0; r < 16; ++r) p0[r] = EXP2R(sc0[r] - m_run);
#pragma unroll
            for (int r = 0; r < 16; ++r) p1[r] = EXP2R(sc1[r] - m_run);
            {
                float s0 = ((p0[0] + p0[1]) + (p0[2] + p0[3])) +
                           ((p0[4] + p0[5]) + (p0[6] + p0[7]));
                float s1 = ((p0[8] + p0[9]) + (p0[10] + p0[11])) +
                           ((p0[12] + p0[13]) + (p0[14] + p0[15]));
                float s2 = ((p1[0] + p1[1]) + (p1[2] + p1[3])) +
                           ((p1[4] + p1[5]) + (p1[6] + p1[7]));
                float s3 = ((p1[8] + p1[9]) + (p1[10] + p1[11])) +
                           ((p1[12] + p1[13]) + (p1[14] + p1[15]));
                l_run += (s0 + s1) + (s2 + s3);
            }

            // ---- pack both P slices to bf16 pairs ----
            unsigned w0[8], w1[8];
#pragma unroll
            for (int b = 0; b < 4; ++b) {
                union { bf16 x; unsigned short u; } c0, c1, c2, c3, d0, d1, d2, d3;
                c0.x = (bf16)p0[4 * b + 0]; c1.x = (bf16)p0[4 * b + 1];
                c2.x = (bf16)p0[4 * b + 2]; c3.x = (bf16)p0[4 * b + 3];
                d0.x = (bf16)p1[4 * b + 0]; d1.x = (bf16)p1[4 * b + 1];
                d2.x = (bf16)p1[4 * b + 2]; d3.x = (bf16)p1[4 * b + 3];
                w0[2 * b]     = (unsigned)c0.u | ((unsigned)c1.u << 16);
                w0[2 * b + 1] = (unsigned)c2.u | ((unsigned)c3.u << 16);
                w1[2 * b]     = (unsigned)d0.u | ((unsigned)d1.u << 16);
                w1[2 * b + 1] = (unsigned)d2.u | ((unsigned)d3.u << 16);
            }

            // ---- PV: O^T[d][q] += Vt_frag * P^T_frag (2 ks x 2 kk) ----
            // Baked V permutation => pf is each lane's OWN w quad (no exchange).
#pragma unroll
            for (int ks = 0; ks < 2; ++ks) {
                const unsigned* w = ks ? w1 : w0;
#pragma unroll
                for (int kk = 0; kk < 2; ++kk) {
                    union { bf16x8 v; unsigned u[4]; } pf;
                    pf.u[0] = w[4 * kk];     pf.u[1] = w[4 * kk + 1];
                    pf.u[2] = w[4 * kk + 2]; pf.u[3] = w[4 * kk + 3];
                    __builtin_amdgcn_s_setprio(1);
#pragma unroll
                    for (int t = 0; t < 2; ++t) {
                        bf16x8 vf = *reinterpret_cast<const bf16x8*>(
                            &sVh[(32 * t + c) * 136 + base + ks * 32 + kk * 16 + 8 * h]);
                        acc[t] = __builtin_amdgcn_mfma_f32_32x32x16_bf16(vf, pf.v, acc[t], 0, 0, 0);
                    }
                    __builtin_amdgcn_s_setprio(0);
                }
            }
        }
    }

    // ---- flash-decoding merge across the two KV halves ----
    float l_tot = l_run + __shfl_xor(l_run, 32);   // full l for this half

    __syncthreads();                                // all compute done; mrg alias safe
    if (half == 1) {
        float4* dst = reinterpret_cast<float4*>(&mrg[(qw * 64 + lane) * 33]);
#pragma unroll
        for (int t = 0; t < 2; ++t)
#pragma unroll
            for (int v = 0; v < 4; ++v)
                dst[t * 4 + v] = make_float4(acc[t][4 * v + 0], acc[t][4 * v + 1],
                                             acc[t][4 * v + 2], acc[t][4 * v + 3]);
        if (lane < 32) { ml[(qw * 32 + lane) * 2 + 0] = m_run;
                         ml[(qw * 32 + lane) * 2 + 1] = l_tot; }
    }
    __syncthreads();

    if (half == 0) {
        float m1 = ml[(qw * 32 + c) * 2 + 0], l1 = ml[(qw * 32 + c) * 2 + 1];
        float mm = fmaxf(m_run, m1);
        float f0 = EXP2R(m_run - mm), f1 = EXP2R(m1 - mm);
        float li = 1.0f / (l_tot * f0 + l1 * f1);
        float g0 = f0 * li, g1 = f1 * li;
        const float4* src = reinterpret_cast<const float4*>(&mrg[(qw * 64 + lane) * 33]);
        float o[2][16];
#pragma unroll
        for (int t = 0; t < 2; ++t)
#pragma unroll
            for (int v = 0; v < 4; ++v) {
                float4 a1 = src[t * 4 + v];
                o[t][4 * v + 0] = acc[t][4 * v + 0] * g0 + a1.x * g1;
                o[t][4 * v + 1] = acc[t][4 * v + 1] * g0 + a1.y * g1;
                o[t][4 * v + 2] = acc[t][4 * v + 2] * g0 + a1.z * g1;
                o[t][4 * v + 3] = acc[t][4 * v + 3] * g0 + a1.w * g1;
            }

        // transpose O^T -> O rows via (reused) wave-private LDS region
        bf16* so = reinterpret_cast<bf16*>(&mrg[(size_t)qw * 64 * 33]);
#pragma unroll
        for (int t = 0; t < 2; ++t)
#pragma unroll
            for (int b = 0; b < 4; ++b) {
                bf16x4 v4 = { (bf16)o[t][4 * b + 0], (bf16)o[t][4 * b + 1],
                              (bf16)o[t][4 * b + 2], (bf16)o[t][4 * b + 3] };
                // d = 32t + 8b + 4h + {0..3}, q = c
                *reinterpret_cast<bf16x4*>(&so[c * 72 + t * 32 + b * 8 + 4 * h]) = v4;
            }
        const int bb = bh >> 4, hh = bh & 15;
#pragma unroll
        for (int i = 0; i < 4; ++i) {
            int chunk = lane + 64 * i;         // 256 chunks = 32 rows x 8
            int row = chunk >> 3, gi = chunk & 7;
            uint4 val = *reinterpret_cast<uint4*>(&so[row * 72 + gi * 8]);
            *reinterpret_cast<uint4*>(
                Ob + ((size_t)(bb * S_ + q0 + qw * 32 + row)) * E_ + hh * 64 + gi * 8) = val;
        }
    }
}

// ---------------------------------------------------------------------------
// Kernel 5: output projection, 64x128 tile (2 blocks/CU).
// ---------------------------------------------------------------------------
__global__ __launch_bounds__(256) void gemm_out(
    const bf16* __restrict__ Ob, const bf16* __restrict__ WT,
    const float* __restrict__ bias, float* __restrict__ out)
{
    __shared__ bf16 sA[64 * 32];
    __shared__ bf16 sB[128 * 32];
    const int tid  = threadIdx.x;
    const int lane = tid & 63;
    const int wave = tid >> 6;
    const int g    = lane >> 4;
    const int r    = lane & 15;
    const int wr   = wave >> 1, wc = wave & 1;   // waves 2x2: 32 rows x 64 cols each
    const int lrow = lane >> 2;
    const int lcol = (lane & 3) * 8;
    const int bm0 = blockIdx.y * 64, bn0 = blockIdx.x * 128;

    f32x4 acc[2][4];
#pragma unroll
    for (int m = 0; m < 2; ++m)
#pragma unroll
        for (int n = 0; n < 4; ++n) acc[m][n] = (f32x4){0.f, 0.f, 0.f, 0.f};

    for (int k0 = 0; k0 < K_; k0 += 32) {
        // A: 64 rows, each wave stages 16
        gload_lds16(Ob + (size_t)(bm0 + wave * 16 + lrow) * K_ + k0 + lcol,
                    &sA[(wave * 16) * 32]);
        // B: 128 rows, each wave stages 32
#pragma unroll
        for (int j = 0; j < 2; ++j) {
            int r0 = wave * 32 + j * 16;
            gload_lds16(WT + (size_t)(bn0 + r0 + lrow) * K_ + k0 + lcol, &sB[r0 * 32]);
        }
        __syncthreads();
        bf16x8 af[2], bfr[4];
#pragma unroll
        for (int m = 0; m < 2; ++m)
            af[m] = *reinterpret_cast<const bf16x8*>(&sA[(wr * 32 + m * 16 + r) * 32 + g * 8]);
#pragma unroll
        for (int n = 0; n < 4; ++n)
            bfr[n] = *reinterpret_cast<const bf16x8*>(&sB[(wc * 64 + n * 16 + r) * 32 + g * 8]);
        __builtin_amdgcn_s_setprio(1);
#pragma unroll
        for (int m = 0; m < 2; ++m)
#pragma unroll
            for (int n = 0; n < 4; ++n)
                acc[m][n] = __builtin_amdgcn_mfma_f32_16x16x32_bf16(af[m], bfr[n], acc[m][n], 0, 0, 0);
        __builtin_amdgcn_s_setprio(0);
        __syncthreads();
    }

#pragma unroll
    for (int m = 0; m < 2; ++m) {
        int ibase = bm0 + wr * 32 + m * 16 + 4 * g;
#pragma unroll
        for (int n = 0; n < 4; ++n) {
            int j = bn0 + wc * 64 + n * 16 + r;
            float bj = bias[j];
#pragma unroll
            for (int jj = 0; jj < 4; ++jj) {
                int row = ibase + jj;
                out[(size_t)row * E_ + j] = acc[m][n][jj] + bj;
            }
        }
    }
}

// ---------------------------------------------------------------------------
extern "C" void kernel_launch(void* const* d_in, const int* in_sizes, int n_in,
                              void* d_out, int out_size, void* d_ws, size_t ws_size,
                              hipStream_t stream)
{
    const float* x     = (const float*)d_in[0];
    const float* W_qkv = (const float*)d_in[1];
    const float* b_qkv = (const float*)d_in[2];
    const float* W_out = (const float*)d_in[3];
    const float* b_out = (const float*)d_in[4];
    float* out = (float*)d_out;

    char* ws = (char*)d_ws;
    bf16* xb    = (bf16*)(ws);                 //  8 MB  [4096][1024]
    bf16* WqkvT = (bf16*)(ws + (8u  << 20));   //  6 MB
    bf16* WoutT = (bf16*)(ws + (14u << 20));   //  2 MB
    bf16* Qb    = (bf16*)(ws + (16u << 20));   //  8 MB  [32][2048][64]
    bf16* Kb    = (bf16*)(ws + (24u << 20));   //  8 MB
    bf16* Vt    = (bf16*)(ws + (32u << 20));   //  8 MB  [32][64][2048] (permuted)
    bf16* Ob    = (bf16*)(ws + (40u << 20));   //  8 MB

    prep_kernel<<<8192, 256, 0, stream>>>(x, xb, W_qkv, WqkvT, W_out, WoutT);
    gemm_qkv<<<dim3(NQKV / 128, M_ / 128), 256, 0, stream>>>(xb, WqkvT, b_qkv, Qb, Kb, Vt);
    attn_kernel<<<dim3(S_ / 128, B_ * H_), 512, 0, stream>>>(Qb, Kb, Vt, Ob);
    gemm_out<<<dim3(E_ / 128, M_ / 64), 256, 0, stream>>>(Ob, WoutT, b_out, out);
}

// Round 20
// 120.754 us; speedup vs baseline: 1.3718x; 1.0519x over previous
//
#include <hip/hip_runtime.h>

// Problem constants
#define B_    2
#define S_    2048
#define E_    1024
#define H_    16
#define D_    64
#define M_    4096      // B*S
#define NQKV  3072
#define K_    1024

typedef __bf16 bf16;
typedef __attribute__((ext_vector_type(4))) __bf16 bf16x4;
typedef __attribute__((ext_vector_type(8))) __bf16 bf16x8;
typedef __attribute__((ext_vector_type(4))) float  f32x4;
typedef __attribute__((ext_vector_type(16))) float f32x16;

// Q pre-scale: 1/sqrt(64) * log2(e)  (softmax done in base-2 domain)
#define QSCALE 0.18033688f

// raw v_exp_f32 (TRANS pipe, 1 inst) — safe: args <= 8 (defer-max bound)
#define EXP2R(x) __builtin_amdgcn_exp2f(x)

// async global->LDS, 16B per lane; LDS dest must be wave-uniform base
__device__ __forceinline__ void gload_lds16(const void* g, void* l) {
    __builtin_amdgcn_global_load_lds(
        (const __attribute__((address_space(1))) void*)g,
        (__attribute__((address_space(3))) void*)l, 16, 0, 0);
}

// ---------------------------------------------------------------------------
// Kernel 1 (merged prep): x cast (blocks 0..4095), W_qkv transpose
// (4096..7167), W_out transpose (7168..8191).
// ---------------------------------------------------------------------------
__global__ __launch_bounds__(256) void prep_kernel(
    const float* __restrict__ x,     bf16* __restrict__ xb,
    const float* __restrict__ W_qkv, bf16* __restrict__ WqkvT,
    const float* __restrict__ W_out, bf16* __restrict__ WoutT)
{
    __shared__ bf16 tile[32][33];
    const int bid = blockIdx.x;
    if (bid < 4096) {
        int i = (bid * 256 + threadIdx.x) * 4;
        float4 v = *reinterpret_cast<const float4*>(x + i);
        bf16x4 o = { (bf16)v.x, (bf16)v.y, (bf16)v.z, (bf16)v.w };
        *reinterpret_cast<bf16x4*>(xb + i) = o;
        return;
    }
    const float* W; bf16* WT; int Ncols, bj, bi;
    if (bid < 4096 + 3072) {
        int t = bid - 4096;                    // W_qkv: 96 x 32 tiles
        W = W_qkv; WT = WqkvT; Ncols = NQKV;
        bj = t % 96; bi = t / 96;
    } else {
        int t = bid - 7168;                    // W_out: 32 x 32 tiles
        W = W_out; WT = WoutT; Ncols = E_;
        bj = t % 32; bi = t / 32;
    }
    int tx = threadIdx.x & 31;
    int ty = threadIdx.x >> 5;
#pragma unroll
    for (int it = 0; it < 4; ++it) {
        int r = ty + it * 8;
        tile[r][tx] = (bf16)W[(size_t)(bi * 32 + r) * Ncols + bj * 32 + tx];
    }
    __syncthreads();
#pragma unroll
    for (int it = 0; it < 4; ++it) {
        int r = ty + it * 8;
        WT[(size_t)(bj * 32 + r) * K_ + bi * 32 + tx] = tile[tx][r];
    }
}

// ---------------------------------------------------------------------------
// Shared GEMM mainloop (m97 structure): C_tile(128x128) = A[M][K] * BT[N][K]^T
// ---------------------------------------------------------------------------
__device__ __forceinline__ void gemm_tile_128(
    const bf16* __restrict__ A, const bf16* __restrict__ BT, int K,
    int bm0, int bn0, f32x4 acc[4][4])
{
    __shared__ bf16 sA[128 * 32];
    __shared__ bf16 sB[128 * 32];
    const int tid  = threadIdx.x;
    const int lane = tid & 63;
    const int wave = tid >> 6;
    const int g    = lane >> 4;
    const int r    = lane & 15;
    const int wr   = wave >> 1, wc = wave & 1;
    const int lrow = lane >> 2;          // 0..15
    const int lcol = (lane & 3) * 8;     // 0,8,16,24 elements

#pragma unroll
    for (int m = 0; m < 4; ++m)
#pragma unroll
        for (int n = 0; n < 4; ++n) acc[m][n] = (f32x4){0.f, 0.f, 0.f, 0.f};

    for (int k0 = 0; k0 < K; k0 += 32) {
#pragma unroll
        for (int j = 0; j < 2; ++j) {
            int r0 = wave * 32 + j * 16;
            gload_lds16(A  + (size_t)(bm0 + r0 + lrow) * K + k0 + lcol, &sA[r0 * 32]);
            gload_lds16(BT + (size_t)(bn0 + r0 + lrow) * K + k0 + lcol, &sB[r0 * 32]);
        }
        __syncthreads();
        bf16x8 af[4], bfr[4];
#pragma unroll
        for (int m = 0; m < 4; ++m)
            af[m] = *reinterpret_cast<const bf16x8*>(&sA[(wr * 64 + m * 16 + r) * 32 + g * 8]);
#pragma unroll
        for (int n = 0; n < 4; ++n)
            bfr[n] = *reinterpret_cast<const bf16x8*>(&sB[(wc * 64 + n * 16 + r) * 32 + g * 8]);
        __builtin_amdgcn_s_setprio(1);
#pragma unroll
        for (int m = 0; m < 4; ++m)
#pragma unroll
            for (int n = 0; n < 4; ++n)
                acc[m][n] = __builtin_amdgcn_mfma_f32_16x16x32_bf16(af[m], bfr[n], acc[m][n], 0, 0, 0);
        __builtin_amdgcn_s_setprio(0);
        __syncthreads();
    }
}

// ---------------------------------------------------------------------------
// Kernel 3: QKV projection -> Q (pre-scaled), K as [BH][S][64]; V transposed
// to Vt [BH][64][S] with the PV key-permutation baked in (s' = swap bits 2,3).
// ---------------------------------------------------------------------------
__global__ __launch_bounds__(256) void gemm_qkv(
    const bf16* __restrict__ xb, const bf16* __restrict__ WT,
    const float* __restrict__ bias,
    bf16* __restrict__ Qb, bf16* __restrict__ Kb, bf16* __restrict__ Vt)
{
    f32x4 acc[4][4];
    const int bid = blockIdx.y * 24 + blockIdx.x;   // 0..767
    const int swz = (bid & 7) * 96 + (bid >> 3);    // bijective
    int bm0 = (swz / 24) * 128, bn0 = (swz % 24) * 128;
    gemm_tile_128(xb, WT, K_, bm0, bn0, acc);

    const int lane = threadIdx.x & 63, wave = threadIdx.x >> 6;
    const int g = lane >> 4, c = lane & 15;
    const int wr = wave >> 1, wc = wave & 1;
#pragma unroll
    for (int m = 0; m < 4; ++m) {
        int ibase = bm0 + wr * 64 + m * 16 + 4 * g;
        int b = ibase >> 11, s = ibase & 2047;   // 4 consecutive rows, same b
        int sp = (s & ~12) | ((s & 4) << 1) | ((s & 8) >> 1);
#pragma unroll
        for (int n = 0; n < 4; ++n) {
            int j = bn0 + wc * 64 + n * 16 + c;
            int h = j / 192, w = j % 192;
            int t = w >> 6, d = w & 63;
            float bj = bias[j];
            if (t == 2) {
                bf16x4 v4 = { (bf16)(acc[m][n][0] + bj), (bf16)(acc[m][n][1] + bj),
                              (bf16)(acc[m][n][2] + bj), (bf16)(acc[m][n][3] + bj) };
                *reinterpret_cast<bf16x4*>(
                    &Vt[((size_t)((b * H_ + h) * D_ + d)) * S_ + sp]) = v4;
            } else {
                bf16* dst = (t == 0) ? Qb : Kb;
                float scale = (t == 0) ? QSCALE : 1.0f;
#pragma unroll
                for (int jj = 0; jj < 4; ++jj) {
                    size_t idx = ((size_t)((b * H_ + h) * S_ + s + jj)) * D_ + d;
                    dst[idx] = (bf16)((acc[m][n][jj] + bj) * scale);
                }
            }
        }
    }
}

// ---------------------------------------------------------------------------
// Kernel 4: flash attention — round-17/19 structure with ONE change: chunked
// XCD swizzle on the block id (512 blocks, 64/XCD = 4 heads per XCD).  K/V
// working set per XCD-L2 drops to ~1 MB -> staging loads become L2 hits,
// shrinking the exposed per-tile staging latency.
// ---------------------------------------------------------------------------
__global__ __launch_bounds__(512, 4) void attn_kernel(
    const bf16* __restrict__ Qb, const bf16* __restrict__ Kb,
    const bf16* __restrict__ Vt, bf16* __restrict__ Ob)
{
    // LDS map (bytes):
    // [0, 36864)       sK[2 half][128][72] bf16
    // [36864, 71680)   sV[2 half][64][136] bf16
    // [0, 33792)       mrg[4*64*33] f32   (ALIAS: used only after compute)
    // [71680, 72704)   ml[4][32][2] f32
    __shared__ __align__(16) char smem[72704];

    // chunked XCD swizzle: flat 0..511, XCD = flat%8 gets 64 contiguous swz
    const int flat = blockIdx.y * 16 + blockIdx.x;
    const int swz  = (flat & 7) * 64 + (flat >> 3);
    const int bh   = swz >> 4;           // b*16 + h   (4 heads per XCD)
    const int q0   = (swz & 15) * 128;

    const int tid = threadIdx.x, lane = tid & 63;
    const int qw   = (tid >> 6) & 3;     // q sub-tile
    const int half = tid >> 8;           // KV half
    const int gtid = tid & 255;          // tid within half-group
    const int c = lane & 31;             // q column (QK), d row (PV A), key row (K frag)
    const int h = lane >> 5;             // k-slice half

    bf16* sKh = reinterpret_cast<bf16*>(smem) + half * (128 * 72);
    bf16* sVh = reinterpret_cast<bf16*>(smem + 36864) + half * (64 * 136);
    float* mrg = reinterpret_cast<float*>(smem);
    float* ml  = reinterpret_cast<float*>(smem + 71680);

    const bf16* Qp = Qb + (size_t)bh * S_ * D_;
    const bf16* Kp = Kb + (size_t)bh * S_ * D_ + (size_t)half * 1024 * D_;
    const bf16* Vp = Vt + (size_t)bh * D_ * S_ + half * 1024;   // [64][2048]

    // Q fragments (B-operand): lane needs Q[q=qrow][d = kk*16 + 8h .. +7]
    const int qrow = q0 + qw * 32 + c;
    bf16x8 qf[4];
#pragma unroll
    for (int kk = 0; kk < 4; ++kk)
        qf[kk] = *reinterpret_cast<const bf16x8*>(Qp + (size_t)qrow * D_ + kk * 16 + 8 * h);

    f32x16 acc[2];
#pragma unroll
    for (int t = 0; t < 2; ++t) acc[t] = (f32x16)(0.f);
    float m_run = -1e30f, l_run = 0.f;

    const int srowK = gtid >> 3, sgiK = (gtid & 7) * 8;    // K: 32 rows/pass x 8 chunks
    const int srowV = gtid >> 4, sgiV = (gtid & 15) * 8;   // V: 16 rows/pass x 16 chunks

    for (int kv0 = 0; kv0 < 1024; kv0 += 128) {
        __syncthreads();
        // stage K[128 keys][64 d] and Vt[64 d][128 keys] for this half
#pragma unroll
        for (int i = 0; i < 4; ++i) {
            int rK = srowK + i * 32;
            *reinterpret_cast<uint4*>(&sKh[rK * 72 + sgiK]) =
                *reinterpret_cast<const uint4*>(Kp + (size_t)(kv0 + rK) * D_ + sgiK);
            int rV = srowV + i * 16;
            *reinterpret_cast<uint4*>(&sVh[rV * 136 + sgiV]) =
                *reinterpret_cast<const uint4*>(Vp + (size_t)rV * S_ + kv0 + sgiV);
        }
        __syncthreads();

#pragma unroll
        for (int ph = 0; ph < 2; ++ph) {
            const int base = ph * 64;
            // ---- QK^T for both 32-key slices (2 independent chains) ----
            f32x16 sc0 = (f32x16)(0.f), sc1 = (f32x16)(0.f);
            __builtin_amdgcn_s_setprio(1);
#pragma unroll
            for (int kk = 0; kk < 4; ++kk) {
                bf16x8 kf0 = *reinterpret_cast<const bf16x8*>(
                    &sKh[(base + c) * 72 + kk * 16 + 8 * h]);
                bf16x8 kf1 = *reinterpret_cast<const bf16x8*>(
                    &sKh[(base + 32 + c) * 72 + kk * 16 + 8 * h]);
                sc0 = __builtin_amdgcn_mfma_f32_32x32x16_bf16(kf0, qf[kk], sc0, 0, 0, 0);
                sc1 = __builtin_amdgcn_mfma_f32_32x32x16_bf16(kf1, qf[kk], sc1, 0, 0, 0);
            }
            __builtin_amdgcn_s_setprio(0);

            // ---- merged online softmax over 64 keys ----
            float a0 = fmaxf(fmaxf(sc0[0], sc0[1]), sc0[2]);
            float a1 = fmaxf(fmaxf(sc0[3], sc0[4]), sc0[5]);
            float a2 = fmaxf(fmaxf(sc0[6], sc0[7]), sc0[8]);
            float a3 = fmaxf(fmaxf(sc0[9], sc0[10]), sc0[11]);
            float a4 = fmaxf(fmaxf(sc0[12], sc0[13]), sc0[14]);
            float a5 = fmaxf(fmaxf(sc1[0], sc1[1]), sc1[2]);
            float a6 = fmaxf(fmaxf(sc1[3], sc1[4]), sc1[5]);
            float a7 = fmaxf(fmaxf(sc1[6], sc1[7]), sc1[8]);
            float a8 = fmaxf(fmaxf(sc1[9], sc1[10]), sc1[11]);
            float a9 = fmaxf(fmaxf(sc1[12], sc1[13]), sc1[14]);
            float b0 = fmaxf(fmaxf(a0, a1), sc0[15]);
            float b1 = fmaxf(fmaxf(a2, a3), a4);
            float b2 = fmaxf(fmaxf(a5, a6), sc1[15]);
            float b3 = fmaxf(fmaxf(a7, a8), a9);
            float vmax = fmaxf(fmaxf(b0, b1), fmaxf(b2, b3));
            vmax = fmaxf(vmax, __shfl_xor(vmax, 32));
            if (__any(vmax > m_run + 8.0f)) {     // defer-max, THR=8 (log2 domain)
                float mnew = fmaxf(m_run, vmax);
                float f = EXP2R(m_run - mnew);
                l_run *= f;
#pragma unroll
                for (int t = 0; t < 2; ++t) acc[t] *= f;
                m_run = mnew;
            }
            float p0[16], p1[16];
#pragma unroll
            for (int r = 0; r < 16; ++r) p0[r] = EXP2R(sc0[r] - m_run);
#pragma unroll
            for (int r = 0; r < 16; ++r) p1[r] = EXP2R(sc1[r] - m_run);
            {
                float s0 = ((p0[0] + p0[1]) + (p0[2] + p0[3])) +
                           ((p0[4] + p0[5]) + (p0[6] + p0[7]));
                float s1 = ((p0[8] + p0[9]) + (p0[10] + p0[11])) +
                           ((p0[12] + p0[13]) + (p0[14] + p0[15]));
                float s2 = ((p1[0] + p1[1]) + (p1[2] + p1[3])) +
                           ((p1[4] + p1[5]) + (p1[6] + p1[7]));
                float s3 = ((p1[8] + p1[9]) + (p1[10] + p1[11])) +
                           ((p1[12] + p1[13]) + (p1[14] + p1[15]));
                l_run += (s0 + s1) + (s2 + s3);
            }

            // ---- pack both P slices to bf16 pairs ----
            unsigned w0[8], w1[8];
#pragma unroll
            for (int b = 0; b < 4; ++b) {
                union { bf16 x; unsigned short u; } c0, c1, c2, c3, d0, d1, d2, d3;
                c0.x = (bf16)p0[4 * b + 0]; c1.x = (bf16)p0[4 * b + 1];
                c2.x = (bf16)p0[4 * b + 2]; c3.x = (bf16)p0[4 * b + 3];
                d0.x = (bf16)p1[4 * b + 0]; d1.x = (bf16)p1[4 * b + 1];
                d2.x = (bf16)p1[4 * b + 2]; d3.x = (bf16)p1[4 * b + 3];
                w0[2 * b]     = (unsigned)c0.u | ((unsigned)c1.u << 16);
                w0[2 * b + 1] = (unsigned)c2.u | ((unsigned)c3.u << 16);
                w1[2 * b]     = (unsigned)d0.u | ((unsigned)d1.u << 16);
                w1[2 * b + 1] = (unsigned)d2.u | ((unsigned)d3.u << 16);
            }

            // ---- PV: O^T[d][q] += Vt_frag * P^T_frag (2 ks x 2 kk) ----
            // Baked V permutation => pf is each lane's OWN w quad (no exchange).
#pragma unroll
            for (int ks = 0; ks < 2; ++ks) {
                const unsigned* w = ks ? w1 : w0;
#pragma unroll
                for (int kk = 0; kk < 2; ++kk) {
                    union { bf16x8 v; unsigned u[4]; } pf;
                    pf.u[0] = w[4 * kk];     pf.u[1] = w[4 * kk + 1];
                    pf.u[2] = w[4 * kk + 2]; pf.u[3] = w[4 * kk + 3];
                    __builtin_amdgcn_s_setprio(1);
#pragma unroll
                    for (int t = 0; t < 2; ++t) {
                        bf16x8 vf = *reinterpret_cast<const bf16x8*>(
                            &sVh[(32 * t + c) * 136 + base + ks * 32 + kk * 16 + 8 * h]);
                        acc[t] = __builtin_amdgcn_mfma_f32_32x32x16_bf16(vf, pf.v, acc[t], 0, 0, 0);
                    }
                    __builtin_amdgcn_s_setprio(0);
                }
            }
        }
    }

    // ---- flash-decoding merge across the two KV halves ----
    float l_tot = l_run + __shfl_xor(l_run, 32);   // full l for this half

    __syncthreads();                                // all compute done; mrg alias safe
    if (half == 1) {
        float4* dst = reinterpret_cast<float4*>(&mrg[(qw * 64 + lane) * 33]);
#pragma unroll
        for (int t = 0; t < 2; ++t)
#pragma unroll
            for (int v = 0; v < 4; ++v)
                dst[t * 4 + v] = make_float4(acc[t][4 * v + 0], acc[t][4 * v + 1],
                                             acc[t][4 * v + 2], acc[t][4 * v + 3]);
        if (lane < 32) { ml[(qw * 32 + lane) * 2 + 0] = m_run;
                         ml[(qw * 32 + lane) * 2 + 1] = l_tot; }
    }
    __syncthreads();

    if (half == 0) {
        float m1 = ml[(qw * 32 + c) * 2 + 0], l1 = ml[(qw * 32 + c) * 2 + 1];
        float mm = fmaxf(m_run, m1);
        float f0 = EXP2R(m_run - mm), f1 = EXP2R(m1 - mm);
        float li = 1.0f / (l_tot * f0 + l1 * f1);
        float g0 = f0 * li, g1 = f1 * li;
        const float4* src = reinterpret_cast<const float4*>(&mrg[(qw * 64 + lane) * 33]);
        float o[2][16];
#pragma unroll
        for (int t = 0; t < 2; ++t)
#pragma unroll
            for (int v = 0; v < 4; ++v) {
                float4 a1 = src[t * 4 + v];
                o[t][4 * v + 0] = acc[t][4 * v + 0] * g0 + a1.x * g1;
                o[t][4 * v + 1] = acc[t][4 * v + 1] * g0 + a1.y * g1;
                o[t][4 * v + 2] = acc[t][4 * v + 2] * g0 + a1.z * g1;
                o[t][4 * v + 3] = acc[t][4 * v + 3] * g0 + a1.w * g1;
            }

        // transpose O^T -> O rows via (reused) wave-private LDS region
        bf16* so = reinterpret_cast<bf16*>(&mrg[(size_t)qw * 64 * 33]);
#pragma unroll
        for (int t = 0; t < 2; ++t)
#pragma unroll
            for (int b = 0; b < 4; ++b) {
                bf16x4 v4 = { (bf16)o[t][4 * b + 0], (bf16)o[t][4 * b + 1],
                              (bf16)o[t][4 * b + 2], (bf16)o[t][4 * b + 3] };
                // d = 32t + 8b + 4h + {0..3}, q = c
                *reinterpret_cast<bf16x4*>(&so[c * 72 + t * 32 + b * 8 + 4 * h]) = v4;
            }
        const int bb = bh >> 4, hh = bh & 15;
#pragma unroll
        for (int i = 0; i < 4; ++i) {
            int chunk = lane + 64 * i;         // 256 chunks = 32 rows x 8
            int row = chunk >> 3, gi = chunk & 7;
            uint4 val = *reinterpret_cast<uint4*>(&so[row * 72 + gi * 8]);
            *reinterpret_cast<uint4*>(
                Ob + ((size_t)(bb * S_ + q0 + qw * 32 + row)) * E_ + hh * 64 + gi * 8) = val;
        }
    }
}

// ---------------------------------------------------------------------------
// Kernel 5: output projection, 64x128 tile (2 blocks/CU).
// ---------------------------------------------------------------------------
__global__ __launch_bounds__(256) void gemm_out(
    const bf16* __restrict__ Ob, const bf16* __restrict__ WT,
    const float* __restrict__ bias, float* __restrict__ out)
{
    __shared__ bf16 sA[64 * 32];
    __shared__ bf16 sB[128 * 32];
    const int tid  = threadIdx.x;
    const int lane = tid & 63;
    const int wave = tid >> 6;
    const int g    = lane >> 4;
    const int r    = lane & 15;
    const int wr   = wave >> 1, wc = wave & 1;   // waves 2x2: 32 rows x 64 cols each
    const int lrow = lane >> 2;
    const int lcol = (lane & 3) * 8;
    const int bm0 = blockIdx.y * 64, bn0 = blockIdx.x * 128;

    f32x4 acc[2][4];
#pragma unroll
    for (int m = 0; m < 2; ++m)
#pragma unroll
        for (int n = 0; n < 4; ++n) acc[m][n] = (f32x4){0.f, 0.f, 0.f, 0.f};

    for (int k0 = 0; k0 < K_; k0 += 32) {
        // A: 64 rows, each wave stages 16
        gload_lds16(Ob + (size_t)(bm0 + wave * 16 + lrow) * K_ + k0 + lcol,
                    &sA[(wave * 16) * 32]);
        // B: 128 rows, each wave stages 32
#pragma unroll
        for (int j = 0; j < 2; ++j) {
            int r0 = wave * 32 + j * 16;
            gload_lds16(WT + (size_t)(bn0 + r0 + lrow) * K_ + k0 + lcol, &sB[r0 * 32]);
        }
        __syncthreads();
        bf16x8 af[2], bfr[4];
#pragma unroll
        for (int m = 0; m < 2; ++m)
            af[m] = *reinterpret_cast<const bf16x8*>(&sA[(wr * 32 + m * 16 + r) * 32 + g * 8]);
#pragma unroll
        for (int n = 0; n < 4; ++n)
            bfr[n] = *reinterpret_cast<const bf16x8*>(&sB[(wc * 64 + n * 16 + r) * 32 + g * 8]);
        __builtin_amdgcn_s_setprio(1);
#pragma unroll
        for (int m = 0; m < 2; ++m)
#pragma unroll
            for (int n = 0; n < 4; ++n)
                acc[m][n] = __builtin_amdgcn_mfma_f32_16x16x32_bf16(af[m], bfr[n], acc[m][n], 0, 0, 0);
        __builtin_amdgcn_s_setprio(0);
        __syncthreads();
    }

#pragma unroll
    for (int m = 0; m < 2; ++m) {
        int ibase = bm0 + wr * 32 + m * 16 + 4 * g;
#pragma unroll
        for (int n = 0; n < 4; ++n) {
            int j = bn0 + wc * 64 + n * 16 + r;
            float bj = bias[j];
#pragma unroll
            for (int jj = 0; jj < 4; ++jj) {
                int row = ibase + jj;
                out[(size_t)row * E_ + j] = acc[m][n][jj] + bj;
            }
        }
    }
}

// ---------------------------------------------------------------------------
extern "C" void kernel_launch(void* const* d_in, const int* in_sizes, int n_in,
                              void* d_out, int out_size, void* d_ws, size_t ws_size,
                              hipStream_t stream)
{
    const float* x     = (const float*)d_in[0];
    const float* W_qkv = (const float*)d_in[1];
    const float* b_qkv = (const float*)d_in[2];
    const float* W_out = (const float*)d_in[3];
    const float* b_out = (const float*)d_in[4];
    float* out = (float*)d_out;

    char* ws = (char*)d_ws;
    bf16* xb    = (bf16*)(ws);                 //  8 MB  [4096][1024]
    bf16* WqkvT = (bf16*)(ws + (8u  << 20));   //  6 MB
    bf16* WoutT = (bf16*)(ws + (14u << 20));   //  2 MB
    bf16* Qb    = (bf16*)(ws + (16u << 20));   //  8 MB  [32][2048][64]
    bf16* Kb    = (bf16*)(ws + (24u << 20));   //  8 MB
    bf16* Vt    = (bf16*)(ws + (32u << 20));   //  8 MB  [32][64][2048] (permuted)
    bf16* Ob    = (bf16*)(ws + (40u << 20));   //  8 MB

    prep_kernel<<<8192, 256, 0, stream>>>(x, xb, W_qkv, WqkvT, W_out, WoutT);
    gemm_qkv<<<dim3(NQKV / 128, M_ / 128), 256, 0, stream>>>(xb, WqkvT, b_qkv, Qb, Kb, Vt);
    attn_kernel<<<dim3(S_ / 128, B_ * H_), 512, 0, stream>>>(Qb, Kb, Vt, Ob);
    gemm_out<<<dim3(E_ / 128, M_ / 64), 256, 0, stream>>>(Ob, WoutT, b_out, out);
}

// Round 21
// 119.744 us; speedup vs baseline: 1.3834x; 1.0084x over previous
//
#include <hip/hip_runtime.h>

// Problem constants
#define B_    2
#define S_    2048
#define E_    1024
#define H_    16
#define D_    64
#define M_    4096      // B*S
#define NQKV  3072
#define K_    1024

typedef __bf16 bf16;
typedef __attribute__((ext_vector_type(4))) __bf16 bf16x4;
typedef __attribute__((ext_vector_type(8))) __bf16 bf16x8;
typedef __attribute__((ext_vector_type(4))) float  f32x4;
typedef __attribute__((ext_vector_type(16))) float f32x16;

// Q pre-scale: 1/sqrt(64) * log2(e)  (softmax done in base-2 domain)
#define QSCALE 0.18033688f

// raw v_exp_f32 (TRANS pipe, 1 inst) — safe: args <= 8 (defer-max bound)
#define EXP2R(x) __builtin_amdgcn_exp2f(x)

// async global->LDS, 16B per lane; LDS dest must be wave-uniform base
__device__ __forceinline__ void gload_lds16(const void* g, void* l) {
    __builtin_amdgcn_global_load_lds(
        (const __attribute__((address_space(1))) void*)g,
        (__attribute__((address_space(3))) void*)l, 16, 0, 0);
}

// ---------------------------------------------------------------------------
// Kernel 1 (merged prep): x cast (blocks 0..4095), W_qkv transpose
// (4096..7167), W_out transpose (7168..8191).
// ---------------------------------------------------------------------------
__global__ __launch_bounds__(256) void prep_kernel(
    const float* __restrict__ x,     bf16* __restrict__ xb,
    const float* __restrict__ W_qkv, bf16* __restrict__ WqkvT,
    const float* __restrict__ W_out, bf16* __restrict__ WoutT)
{
    __shared__ bf16 tile[32][33];
    const int bid = blockIdx.x;
    if (bid < 4096) {
        int i = (bid * 256 + threadIdx.x) * 4;
        float4 v = *reinterpret_cast<const float4*>(x + i);
        bf16x4 o = { (bf16)v.x, (bf16)v.y, (bf16)v.z, (bf16)v.w };
        *reinterpret_cast<bf16x4*>(xb + i) = o;
        return;
    }
    const float* W; bf16* WT; int Ncols, bj, bi;
    if (bid < 4096 + 3072) {
        int t = bid - 4096;                    // W_qkv: 96 x 32 tiles
        W = W_qkv; WT = WqkvT; Ncols = NQKV;
        bj = t % 96; bi = t / 96;
    } else {
        int t = bid - 7168;                    // W_out: 32 x 32 tiles
        W = W_out; WT = WoutT; Ncols = E_;
        bj = t % 32; bi = t / 32;
    }
    int tx = threadIdx.x & 31;
    int ty = threadIdx.x >> 5;
#pragma unroll
    for (int it = 0; it < 4; ++it) {
        int r = ty + it * 8;
        tile[r][tx] = (bf16)W[(size_t)(bi * 32 + r) * Ncols + bj * 32 + tx];
    }
    __syncthreads();
#pragma unroll
    for (int it = 0; it < 4; ++it) {
        int r = ty + it * 8;
        WT[(size_t)(bj * 32 + r) * K_ + bi * 32 + tx] = tile[tx][r];
    }
}

// ---------------------------------------------------------------------------
// Shared GEMM mainloop (m97 structure): C_tile(128x128) = A[M][K] * BT[N][K]^T
// ---------------------------------------------------------------------------
__device__ __forceinline__ void gemm_tile_128(
    const bf16* __restrict__ A, const bf16* __restrict__ BT, int K,
    int bm0, int bn0, f32x4 acc[4][4])
{
    __shared__ bf16 sA[128 * 32];
    __shared__ bf16 sB[128 * 32];
    const int tid  = threadIdx.x;
    const int lane = tid & 63;
    const int wave = tid >> 6;
    const int g    = lane >> 4;
    const int r    = lane & 15;
    const int wr   = wave >> 1, wc = wave & 1;
    const int lrow = lane >> 2;          // 0..15
    const int lcol = (lane & 3) * 8;     // 0,8,16,24 elements

#pragma unroll
    for (int m = 0; m < 4; ++m)
#pragma unroll
        for (int n = 0; n < 4; ++n) acc[m][n] = (f32x4){0.f, 0.f, 0.f, 0.f};

    for (int k0 = 0; k0 < K; k0 += 32) {
#pragma unroll
        for (int j = 0; j < 2; ++j) {
            int r0 = wave * 32 + j * 16;
            gload_lds16(A  + (size_t)(bm0 + r0 + lrow) * K + k0 + lcol, &sA[r0 * 32]);
            gload_lds16(BT + (size_t)(bn0 + r0 + lrow) * K + k0 + lcol, &sB[r0 * 32]);
        }
        __syncthreads();
        bf16x8 af[4], bfr[4];
#pragma unroll
        for (int m = 0; m < 4; ++m)
            af[m] = *reinterpret_cast<const bf16x8*>(&sA[(wr * 64 + m * 16 + r) * 32 + g * 8]);
#pragma unroll
        for (int n = 0; n < 4; ++n)
            bfr[n] = *reinterpret_cast<const bf16x8*>(&sB[(wc * 64 + n * 16 + r) * 32 + g * 8]);
        __builtin_amdgcn_s_setprio(1);
#pragma unroll
        for (int m = 0; m < 4; ++m)
#pragma unroll
            for (int n = 0; n < 4; ++n)
                acc[m][n] = __builtin_amdgcn_mfma_f32_16x16x32_bf16(af[m], bfr[n], acc[m][n], 0, 0, 0);
        __builtin_amdgcn_s_setprio(0);
        __syncthreads();
    }
}

// ---------------------------------------------------------------------------
// Kernel 3: QKV projection -> Q (pre-scaled), K as [BH][S][64]; V transposed
// to Vt [BH][64][S] with the PV key-permutation baked in (s' = swap bits 2,3).
// ---------------------------------------------------------------------------
__global__ __launch_bounds__(256) void gemm_qkv(
    const bf16* __restrict__ xb, const bf16* __restrict__ WT,
    const float* __restrict__ bias,
    bf16* __restrict__ Qb, bf16* __restrict__ Kb, bf16* __restrict__ Vt)
{
    f32x4 acc[4][4];
    const int bid = blockIdx.y * 24 + blockIdx.x;   // 0..767
    const int swz = (bid & 7) * 96 + (bid >> 3);    // bijective
    int bm0 = (swz / 24) * 128, bn0 = (swz % 24) * 128;
    gemm_tile_128(xb, WT, K_, bm0, bn0, acc);

    const int lane = threadIdx.x & 63, wave = threadIdx.x >> 6;
    const int g = lane >> 4, c = lane & 15;
    const int wr = wave >> 1, wc = wave & 1;
#pragma unroll
    for (int m = 0; m < 4; ++m) {
        int ibase = bm0 + wr * 64 + m * 16 + 4 * g;
        int b = ibase >> 11, s = ibase & 2047;   // 4 consecutive rows, same b
        int sp = (s & ~12) | ((s & 4) << 1) | ((s & 8) >> 1);
#pragma unroll
        for (int n = 0; n < 4; ++n) {
            int j = bn0 + wc * 64 + n * 16 + c;
            int h = j / 192, w = j % 192;
            int t = w >> 6, d = w & 63;
            float bj = bias[j];
            if (t == 2) {
                bf16x4 v4 = { (bf16)(acc[m][n][0] + bj), (bf16)(acc[m][n][1] + bj),
                              (bf16)(acc[m][n][2] + bj), (bf16)(acc[m][n][3] + bj) };
                *reinterpret_cast<bf16x4*>(
                    &Vt[((size_t)((b * H_ + h) * D_ + d)) * S_ + sp]) = v4;
            } else {
                bf16* dst = (t == 0) ? Qb : Kb;
                float scale = (t == 0) ? QSCALE : 1.0f;
#pragma unroll
                for (int jj = 0; jj < 4; ++jj) {
                    size_t idx = ((size_t)((b * H_ + h) * S_ + s + jj)) * D_ + d;
                    dst[idx] = (bf16)((acc[m][n][jj] + bj) * scale);
                }
            }
        }
    }
}

// ---------------------------------------------------------------------------
// Kernel 4: flash attention — round-20 version (best: 57.7 us).  Chunked
// XCD swizzle, swapped QK^T 32x32, 2-way KV-split, KVBLK=128, merged
// softmax, raw v_exp_f32, baked V permutation.
// ---------------------------------------------------------------------------
__global__ __launch_bounds__(512, 4) void attn_kernel(
    const bf16* __restrict__ Qb, const bf16* __restrict__ Kb,
    const bf16* __restrict__ Vt, bf16* __restrict__ Ob)
{
    // LDS map (bytes):
    // [0, 36864)       sK[2 half][128][72] bf16
    // [36864, 71680)   sV[2 half][64][136] bf16
    // [0, 33792)       mrg[4*64*33] f32   (ALIAS: used only after compute)
    // [71680, 72704)   ml[4][32][2] f32
    __shared__ __align__(16) char smem[72704];

    // chunked XCD swizzle: flat 0..511, XCD = flat%8 gets 64 contiguous swz
    const int flat = blockIdx.y * 16 + blockIdx.x;
    const int swz  = (flat & 7) * 64 + (flat >> 3);
    const int bh   = swz >> 4;           // b*16 + h   (4 heads per XCD)
    const int q0   = (swz & 15) * 128;

    const int tid = threadIdx.x, lane = tid & 63;
    const int qw   = (tid >> 6) & 3;     // q sub-tile
    const int half = tid >> 8;           // KV half
    const int gtid = tid & 255;          // tid within half-group
    const int c = lane & 31;             // q column (QK), d row (PV A), key row (K frag)
    const int h = lane >> 5;             // k-slice half

    bf16* sKh = reinterpret_cast<bf16*>(smem) + half * (128 * 72);
    bf16* sVh = reinterpret_cast<bf16*>(smem + 36864) + half * (64 * 136);
    float* mrg = reinterpret_cast<float*>(smem);
    float* ml  = reinterpret_cast<float*>(smem + 71680);

    const bf16* Qp = Qb + (size_t)bh * S_ * D_;
    const bf16* Kp = Kb + (size_t)bh * S_ * D_ + (size_t)half * 1024 * D_;
    const bf16* Vp = Vt + (size_t)bh * D_ * S_ + half * 1024;   // [64][2048]

    // Q fragments (B-operand): lane needs Q[q=qrow][d = kk*16 + 8h .. +7]
    const int qrow = q0 + qw * 32 + c;
    bf16x8 qf[4];
#pragma unroll
    for (int kk = 0; kk < 4; ++kk)
        qf[kk] = *reinterpret_cast<const bf16x8*>(Qp + (size_t)qrow * D_ + kk * 16 + 8 * h);

    f32x16 acc[2];
#pragma unroll
    for (int t = 0; t < 2; ++t) acc[t] = (f32x16)(0.f);
    float m_run = -1e30f, l_run = 0.f;

    const int srowK = gtid >> 3, sgiK = (gtid & 7) * 8;    // K: 32 rows/pass x 8 chunks
    const int srowV = gtid >> 4, sgiV = (gtid & 15) * 8;   // V: 16 rows/pass x 16 chunks

    for (int kv0 = 0; kv0 < 1024; kv0 += 128) {
        __syncthreads();
        // stage K[128 keys][64 d] and Vt[64 d][128 keys] for this half
#pragma unroll
        for (int i = 0; i < 4; ++i) {
            int rK = srowK + i * 32;
            *reinterpret_cast<uint4*>(&sKh[rK * 72 + sgiK]) =
                *reinterpret_cast<const uint4*>(Kp + (size_t)(kv0 + rK) * D_ + sgiK);
            int rV = srowV + i * 16;
            *reinterpret_cast<uint4*>(&sVh[rV * 136 + sgiV]) =
                *reinterpret_cast<const uint4*>(Vp + (size_t)rV * S_ + kv0 + sgiV);
        }
        __syncthreads();

#pragma unroll
        for (int ph = 0; ph < 2; ++ph) {
            const int base = ph * 64;
            // ---- QK^T for both 32-key slices (2 independent chains) ----
            f32x16 sc0 = (f32x16)(0.f), sc1 = (f32x16)(0.f);
            __builtin_amdgcn_s_setprio(1);
#pragma unroll
            for (int kk = 0; kk < 4; ++kk) {
                bf16x8 kf0 = *reinterpret_cast<const bf16x8*>(
                    &sKh[(base + c) * 72 + kk * 16 + 8 * h]);
                bf16x8 kf1 = *reinterpret_cast<const bf16x8*>(
                    &sKh[(base + 32 + c) * 72 + kk * 16 + 8 * h]);
                sc0 = __builtin_amdgcn_mfma_f32_32x32x16_bf16(kf0, qf[kk], sc0, 0, 0, 0);
                sc1 = __builtin_amdgcn_mfma_f32_32x32x16_bf16(kf1, qf[kk], sc1, 0, 0, 0);
            }
            __builtin_amdgcn_s_setprio(0);

            // ---- merged online softmax over 64 keys ----
            float a0 = fmaxf(fmaxf(sc0[0], sc0[1]), sc0[2]);
            float a1 = fmaxf(fmaxf(sc0[3], sc0[4]), sc0[5]);
            float a2 = fmaxf(fmaxf(sc0[6], sc0[7]), sc0[8]);
            float a3 = fmaxf(fmaxf(sc0[9], sc0[10]), sc0[11]);
            float a4 = fmaxf(fmaxf(sc0[12], sc0[13]), sc0[14]);
            float a5 = fmaxf(fmaxf(sc1[0], sc1[1]), sc1[2]);
            float a6 = fmaxf(fmaxf(sc1[3], sc1[4]), sc1[5]);
            float a7 = fmaxf(fmaxf(sc1[6], sc1[7]), sc1[8]);
            float a8 = fmaxf(fmaxf(sc1[9], sc1[10]), sc1[11]);
            float a9 = fmaxf(fmaxf(sc1[12], sc1[13]), sc1[14]);
            float b0 = fmaxf(fmaxf(a0, a1), sc0[15]);
            float b1 = fmaxf(fmaxf(a2, a3), a4);
            float b2 = fmaxf(fmaxf(a5, a6), sc1[15]);
            float b3 = fmaxf(fmaxf(a7, a8), a9);
            float vmax = fmaxf(fmaxf(b0, b1), fmaxf(b2, b3));
            vmax = fmaxf(vmax, __shfl_xor(vmax, 32));
            if (__any(vmax > m_run + 8.0f)) {     // defer-max, THR=8 (log2 domain)
                float mnew = fmaxf(m_run, vmax);
                float f = EXP2R(m_run - mnew);
                l_run *= f;
#pragma unroll
                for (int t = 0; t < 2; ++t) acc[t] *= f;
                m_run = mnew;
            }
            float p0[16], p1[16];
#pragma unroll
            for (int r = 0; r < 16; ++r) p0[r] = EXP2R(sc0[r] - m_run);
#pragma unroll
            for (int r = 0; r < 16; ++r) p1[r] = EXP2R(sc1[r] - m_run);
            {
                float s0 = ((p0[0] + p0[1]) + (p0[2] + p0[3])) +
                           ((p0[4] + p0[5]) + (p0[6] + p0[7]));
                float s1 = ((p0[8] + p0[9]) + (p0[10] + p0[11])) +
                           ((p0[12] + p0[13]) + (p0[14] + p0[15]));
                float s2 = ((p1[0] + p1[1]) + (p1[2] + p1[3])) +
                           ((p1[4] + p1[5]) + (p1[6] + p1[7]));
                float s3 = ((p1[8] + p1[9]) + (p1[10] + p1[11])) +
                           ((p1[12] + p1[13]) + (p1[14] + p1[15]));
                l_run += (s0 + s1) + (s2 + s3);
            }

            // ---- pack both P slices to bf16 pairs ----
            unsigned w0[8], w1[8];
#pragma unroll
            for (int b = 0; b < 4; ++b) {
                union { bf16 x; unsigned short u; } c0, c1, c2, c3, d0, d1, d2, d3;
                c0.x = (bf16)p0[4 * b + 0]; c1.x = (bf16)p0[4 * b + 1];
                c2.x = (bf16)p0[4 * b + 2]; c3.x = (bf16)p0[4 * b + 3];
                d0.x = (bf16)p1[4 * b + 0]; d1.x = (bf16)p1[4 * b + 1];
                d2.x = (bf16)p1[4 * b + 2]; d3.x = (bf16)p1[4 * b + 3];
                w0[2 * b]     = (unsigned)c0.u | ((unsigned)c1.u << 16);
                w0[2 * b + 1] = (unsigned)c2.u | ((unsigned)c3.u << 16);
                w1[2 * b]     = (unsigned)d0.u | ((unsigned)d1.u << 16);
                w1[2 * b + 1] = (unsigned)d2.u | ((unsigned)d3.u << 16);
            }

            // ---- PV: O^T[d][q] += Vt_frag * P^T_frag (2 ks x 2 kk) ----
            // Baked V permutation => pf is each lane's OWN w quad (no exchange).
#pragma unroll
            for (int ks = 0; ks < 2; ++ks) {
                const unsigned* w = ks ? w1 : w0;
#pragma unroll
                for (int kk = 0; kk < 2; ++kk) {
                    union { bf16x8 v; unsigned u[4]; } pf;
                    pf.u[0] = w[4 * kk];     pf.u[1] = w[4 * kk + 1];
                    pf.u[2] = w[4 * kk + 2]; pf.u[3] = w[4 * kk + 3];
                    __builtin_amdgcn_s_setprio(1);
#pragma unroll
                    for (int t = 0; t < 2; ++t) {
                        bf16x8 vf = *reinterpret_cast<const bf16x8*>(
                            &sVh[(32 * t + c) * 136 + base + ks * 32 + kk * 16 + 8 * h]);
                        acc[t] = __builtin_amdgcn_mfma_f32_32x32x16_bf16(vf, pf.v, acc[t], 0, 0, 0);
                    }
                    __builtin_amdgcn_s_setprio(0);
                }
            }
        }
    }

    // ---- flash-decoding merge across the two KV halves ----
    float l_tot = l_run + __shfl_xor(l_run, 32);   // full l for this half

    __syncthreads();                                // all compute done; mrg alias safe
    if (half == 1) {
        float4* dst = reinterpret_cast<float4*>(&mrg[(qw * 64 + lane) * 33]);
#pragma unroll
        for (int t = 0; t < 2; ++t)
#pragma unroll
            for (int v = 0; v < 4; ++v)
                dst[t * 4 + v] = make_float4(acc[t][4 * v + 0], acc[t][4 * v + 1],
                                             acc[t][4 * v + 2], acc[t][4 * v + 3]);
        if (lane < 32) { ml[(qw * 32 + lane) * 2 + 0] = m_run;
                         ml[(qw * 32 + lane) * 2 + 1] = l_tot; }
    }
    __syncthreads();

    if (half == 0) {
        float m1 = ml[(qw * 32 + c) * 2 + 0], l1 = ml[(qw * 32 + c) * 2 + 1];
        float mm = fmaxf(m_run, m1);
        float f0 = EXP2R(m_run - mm), f1 = EXP2R(m1 - mm);
        float li = 1.0f / (l_tot * f0 + l1 * f1);
        float g0 = f0 * li, g1 = f1 * li;
        const float4* src = reinterpret_cast<const float4*>(&mrg[(qw * 64 + lane) * 33]);
        float o[2][16];
#pragma unroll
        for (int t = 0; t < 2; ++t)
#pragma unroll
            for (int v = 0; v < 4; ++v) {
                float4 a1 = src[t * 4 + v];
                o[t][4 * v + 0] = acc[t][4 * v + 0] * g0 + a1.x * g1;
                o[t][4 * v + 1] = acc[t][4 * v + 1] * g0 + a1.y * g1;
                o[t][4 * v + 2] = acc[t][4 * v + 2] * g0 + a1.z * g1;
                o[t][4 * v + 3] = acc[t][4 * v + 3] * g0 + a1.w * g1;
            }

        // transpose O^T -> O rows via (reused) wave-private LDS region
        bf16* so = reinterpret_cast<bf16*>(&mrg[(size_t)qw * 64 * 33]);
#pragma unroll
        for (int t = 0; t < 2; ++t)
#pragma unroll
            for (int b = 0; b < 4; ++b) {
                bf16x4 v4 = { (bf16)o[t][4 * b + 0], (bf16)o[t][4 * b + 1],
                              (bf16)o[t][4 * b + 2], (bf16)o[t][4 * b + 3] };
                // d = 32t + 8b + 4h + {0..3}, q = c
                *reinterpret_cast<bf16x4*>(&so[c * 72 + t * 32 + b * 8 + 4 * h]) = v4;
            }
        const int bb = bh >> 4, hh = bh & 15;
#pragma unroll
        for (int i = 0; i < 4; ++i) {
            int chunk = lane + 64 * i;         // 256 chunks = 32 rows x 8
            int row = chunk >> 3, gi = chunk & 7;
            uint4 val = *reinterpret_cast<uint4*>(&so[row * 72 + gi * 8]);
            *reinterpret_cast<uint4*>(
                Ob + ((size_t)(bb * S_ + q0 + qw * 32 + row)) * E_ + hh * 64 + gi * 8) = val;
        }
    }
}

// ---------------------------------------------------------------------------
// Kernel 5: output projection, 64x128 tile (2 blocks/CU) + chunked XCD
// swizzle (512 blocks, 64/XCD = 8 contiguous M-tile rows per XCD: 1 MB Ob
// slice + 2 MB WoutT resident per XCD-L2).
// ---------------------------------------------------------------------------
__global__ __launch_bounds__(256) void gemm_out(
    const bf16* __restrict__ Ob, const bf16* __restrict__ WT,
    const float* __restrict__ bias, float* __restrict__ out)
{
    __shared__ bf16 sA[64 * 32];
    __shared__ bf16 sB[128 * 32];
    const int tid  = threadIdx.x;
    const int lane = tid & 63;
    const int wave = tid >> 6;
    const int g    = lane >> 4;
    const int r    = lane & 15;
    const int wr   = wave >> 1, wc = wave & 1;   // waves 2x2: 32 rows x 64 cols each
    const int lrow = lane >> 2;
    const int lcol = (lane & 3) * 8;
    // chunked XCD swizzle (512 blocks, bijective)
    const int flat = blockIdx.y * 8 + blockIdx.x;
    const int swz  = (flat & 7) * 64 + (flat >> 3);
    const int bm0 = (swz >> 3) * 64, bn0 = (swz & 7) * 128;

    f32x4 acc[2][4];
#pragma unroll
    for (int m = 0; m < 2; ++m)
#pragma unroll
        for (int n = 0; n < 4; ++n) acc[m][n] = (f32x4){0.f, 0.f, 0.f, 0.f};

    for (int k0 = 0; k0 < K_; k0 += 32) {
        // A: 64 rows, each wave stages 16
        gload_lds16(Ob + (size_t)(bm0 + wave * 16 + lrow) * K_ + k0 + lcol,
                    &sA[(wave * 16) * 32]);
        // B: 128 rows, each wave stages 32
#pragma unroll
        for (int j = 0; j < 2; ++j) {
            int r0 = wave * 32 + j * 16;
            gload_lds16(WT + (size_t)(bn0 + r0 + lrow) * K_ + k0 + lcol, &sB[r0 * 32]);
        }
        __syncthreads();
        bf16x8 af[2], bfr[4];
#pragma unroll
        for (int m = 0; m < 2; ++m)
            af[m] = *reinterpret_cast<const bf16x8*>(&sA[(wr * 32 + m * 16 + r) * 32 + g * 8]);
#pragma unroll
        for (int n = 0; n < 4; ++n)
            bfr[n] = *reinterpret_cast<const bf16x8*>(&sB[(wc * 64 + n * 16 + r) * 32 + g * 8]);
        __builtin_amdgcn_s_setprio(1);
#pragma unroll
        for (int m = 0; m < 2; ++m)
#pragma unroll
            for (int n = 0; n < 4; ++n)
                acc[m][n] = __builtin_amdgcn_mfma_f32_16x16x32_bf16(af[m], bfr[n], acc[m][n], 0, 0, 0);
        __builtin_amdgcn_s_setprio(0);
        __syncthreads();
    }

#pragma unroll
    for (int m = 0; m < 2; ++m) {
        int ibase = bm0 + wr * 32 + m * 16 + 4 * g;
#pragma unroll
        for (int n = 0; n < 4; ++n) {
            int j = bn0 + wc * 64 + n * 16 + r;
            float bj = bias[j];
#pragma unroll
            for (int jj = 0; jj < 4; ++jj) {
                int row = ibase + jj;
                out[(size_t)row * E_ + j] = acc[m][n][jj] + bj;
            }
        }
    }
}

// ---------------------------------------------------------------------------
extern "C" void kernel_launch(void* const* d_in, const int* in_sizes, int n_in,
                              void* d_out, int out_size, void* d_ws, size_t ws_size,
                              hipStream_t stream)
{
    const float* x     = (const float*)d_in[0];
    const float* W_qkv = (const float*)d_in[1];
    const float* b_qkv = (const float*)d_in[2];
    const float* W_out = (const float*)d_in[3];
    const float* b_out = (const float*)d_in[4];
    float* out = (float*)d_out;

    char* ws = (char*)d_ws;
    bf16* xb    = (bf16*)(ws);                 //  8 MB  [4096][1024]
    bf16* WqkvT = (bf16*)(ws + (8u  << 20));   //  6 MB
    bf16* WoutT = (bf16*)(ws + (14u << 20));   //  2 MB
    bf16* Qb    = (bf16*)(ws + (16u << 20));   //  8 MB  [32][2048][64]
    bf16* Kb    = (bf16*)(ws + (24u << 20));   //  8 MB
    bf16* Vt    = (bf16*)(ws + (32u << 20));   //  8 MB  [32][64][2048] (permuted)
    bf16* Ob    = (bf16*)(ws + (40u << 20));   //  8 MB

    prep_kernel<<<8192, 256, 0, stream>>>(x, xb, W_qkv, WqkvT, W_out, WoutT);
    gemm_qkv<<<dim3(NQKV / 128, M_ / 128), 256, 0, stream>>>(xb, WqkvT, b_qkv, Qb, Kb, Vt);
    attn_kernel<<<dim3(S_ / 128, B_ * H_), 512, 0, stream>>>(Qb, Kb, Vt, Ob);
    gemm_out<<<dim3(E_ / 128, M_ / 64), 256, 0, stream>>>(Ob, WoutT, b_out, out);
}